// Round 6
// baseline (638.865 us; speedup 1.0000x reference)
//
#include <hip/hip_runtime.h>
#include <cstdint>

#define DEV static __device__ __forceinline__

typedef __attribute__((ext_vector_type(8))) short short8v;     // 8 x bf16 bits
typedef __attribute__((ext_vector_type(4))) float f32x4;
typedef __attribute__((ext_vector_type(4))) float fl4;
typedef __attribute__((ext_vector_type(4))) unsigned short us4;
typedef __attribute__((ext_vector_type(8))) unsigned short us8;

DEV float b2f(unsigned short u) {
  union { unsigned int i; float f; } c; c.i = ((unsigned int)u) << 16; return c.f;
}
DEV unsigned short f2b(float f) {   // RNE float -> bf16 bits
  union { float f; unsigned int i; } c; c.f = f;
  unsigned int u = c.i;
  u += 0x7fffu + ((u >> 16) & 1u);
  return (unsigned short)(u >> 16);
}

DEV void gload16(const void* g, void* l) {  // async global->LDS, 16B/lane
  __builtin_amdgcn_global_load_lds(
      (const __attribute__((address_space(1))) unsigned int*)g,
      (__attribute__((address_space(3))) unsigned int*)l, 16, 0, 0);
}

DEV float red16(float v) {  // reduce across 16 lanes sharing lk (xor low 4 bits)
  v += __shfl_xor(v, 1); v += __shfl_xor(v, 2);
  v += __shfl_xor(v, 4); v += __shfl_xor(v, 8);
  return v;
}
DEV float red4lk(float v) { // reduce across the 4 lk groups (xor bits 4,5)
  v += __shfl_xor(v, 16); v += __shfl_xor(v, 32);
  return v;
}

// ---------------- elementwise f32 -> bf16 ----------------
__global__ __launch_bounds__(256) void k_f32_to_bf16(const float* __restrict__ src,
                                                     unsigned short* __restrict__ dst, long n) {
  long i = ((long)blockIdx.x * 256 + threadIdx.x) * 4;
  if (i >= n) return;
  fl4 v = *(const fl4*)(src + i);
  us4 o;
  o[0] = f2b(v[0]); o[1] = f2b(v[1]); o[2] = f2b(v[2]); o[3] = f2b(v[3]);
  *(us4*)(dst + i) = o;
}

// ---------------- concat biases into 3072-float buffer ----------------
__global__ __launch_bounds__(256) void k_bias_cat(const float* __restrict__ bq,
                                                  const float* __restrict__ bk,
                                                  const float* __restrict__ bv,
                                                  float* __restrict__ o) {
  const int t = blockIdx.x * 256 + threadIdx.x;   // 3072
  o[t] = t < 1024 ? bq[t] : (t < 2048 ? bk[t - 1024] : bv[t - 2048]);
}

// ---------------- finalize inverse norms ----------------
__global__ __launch_bounds__(256) void k_norms_fin(const float* __restrict__ pq,
                                                   const float* __restrict__ pk,
                                                   float* __restrict__ invq, float* __restrict__ invk) {
  const int gid = blockIdx.x * 256 + threadIdx.x;   // 16384
  invq[gid] = rsqrtf(pq[gid]);
  invk[gid] = rsqrtf(pk[gid]);
}

// ---------------- finalize tailor: 1/(L + rowsum(S) + eps*invq*colsum(Q)) ----------------
__global__ __launch_bounds__(256) void k_tailor_fin(const float* __restrict__ Srow,
                                                    const float* __restrict__ invq,
                                                    const float* __restrict__ qsum,
                                                    float* __restrict__ tailor) {
  const int gid = blockIdx.x * 256 + threadIdx.x;   // 16384
  tailor[gid] = 1.0f / (1024.0f + Srow[gid] + 1e-6f * invq[gid] * qsum[gid]);
}

// ---------------- transpose+scale: (B,2048,1024) -> (B,1024,2048), dst row j scaled ----------------
__global__ __launch_bounds__(256) void k_transpose_scale(const unsigned short* __restrict__ Q,
                                                         const float* __restrict__ scale,
                                                         unsigned short* __restrict__ QT) {
  __shared__ unsigned short tile[64][68];
  const int c0 = blockIdx.x * 64, n0 = blockIdx.y * 64, b = blockIdx.z;
  const int jr = (threadIdx.x & 15) * 4;
  const int ir = threadIdx.x >> 4;
  const unsigned short* src = Q + ((long)b * 2048 + c0) * 1024 + n0;
#pragma unroll
  for (int p = 0; p < 4; ++p) {
    int i = ir + p * 16;
    *(us4*)&tile[i][jr] = *(const us4*)(src + (long)i * 1024 + jr);
  }
  __syncthreads();
  unsigned short* dst = QT + ((long)b * 1024 + n0) * 2048 + c0;
#pragma unroll
  for (int p = 0; p < 4; ++p) {
    int j = ir + p * 16;
    const float s = scale[b * 1024 + n0 + j];
    us4 o;
    o[0] = f2b(b2f(tile[jr + 0][j]) * s);
    o[1] = f2b(b2f(tile[jr + 1][j]) * s);
    o[2] = f2b(b2f(tile[jr + 2][j]) * s);
    o[3] = f2b(b2f(tile[jr + 3][j]) * s);
    *(us4*)(dst + (long)j * 2048 + jr) = o;
  }
}

// ---------------- 256x256 NT GEMM, BK=32, 8 waves (2Mx4N), 4-deep LDS pipeline ----------
// Pipeline: 4 K-tile buffers; at iter t stage tile t+3 into buf (t+3)&3 (== (t-1)&3,
// consumed at iter t-1, stage issued after that iter's end barrier -> no hazard), then
// s_waitcnt vmcnt(12) (3 tiles x 4 loads in flight) -> prefetch distance ~3 iters ~ HBM latency.
// LDS chunk-swizzle (T2, both-sides): logical (row, chunk c in [0,4)) stored at physical
// slot row*4 + (c ^ ((row>>1)&3)); stage pre-swizzles the GLOBAL source chunk per lane,
// read applies the same XOR. Bank-conflict-free (verified: SQ_LDS_BANK_CONFLICT == 0).
// C[m][n] = sum_k A[m][k] * Bt[n][k]; out col-stride fixed 1024.
// EPI 1: final fused fp32 epilogue (residual bf16 xh, Vsum, tailor, gamma).
// EPI 4: bf16 out + per-row atomic sum into r4[bz*1024+row].                  [S]
// EPI 5: merged QKV: out segment by col (Q/K/V), bias, fused reductions.
template<int EPI>
__global__ __launch_bounds__(512)
void k_g256(const unsigned short* __restrict__ A,
            const unsigned short* __restrict__ Bt,
            void* __restrict__ O0, void* __restrict__ O1, void* __restrict__ O2,
            int K, long sA, long sB, long sC,
            const float* __restrict__ bias,
            float* __restrict__ r1, float* __restrict__ r2,
            float* __restrict__ r3, float* __restrict__ r4,
            const unsigned short* __restrict__ xh,
            const float* __restrict__ Vsum,
            const float* __restrict__ tailor,
            const float* __restrict__ gptr) {
  __shared__ __align__(16) unsigned short As[4][8192];   // 4 x 256x32 bf16 = 64 KiB
  __shared__ __align__(16) unsigned short Bs[4][8192];   // 64 KiB   (total 128 KiB)

  const int tid = threadIdx.x;
  const int wv = tid >> 6, lane = tid & 63;
  const int wr = wv >> 2, wcn = wv & 3;          // 2 x 4 wave grid
  const int l15 = lane & 15, lk = lane >> 4;

  // XCD-bijective swizzle over (x,y); nwg % 8 == 0 for all grids used
  const int nx = gridDim.x;
  const int nwg = nx * gridDim.y;
  const int lin = blockIdx.y * nx + blockIdx.x;
  const int cpx = nwg >> 3;
  const int wg = (lin & 7) * cpx + (lin >> 3);
  const int bn = wg % nx;
  const int bm = wg / nx;
  const int bz = blockIdx.z;

  const unsigned short* Ab = A + (long)bz * sA + (long)bm * 256 * K;
  const unsigned short* Bb = Bt + (long)bz * sB + (long)bn * 256 * K;

  // staging: lane tid fills physical slot (q*512 + tid); logical (row, chunk):
  // row = q*128 + (tid>>2), chunk = (tid&3) ^ ((row>>1)&3) = (tid&3) ^ ((tid>>3)&3).
  const int scsw = (tid & 3) ^ ((tid >> 3) & 3);
  const long soff = (long)(tid >> 2) * K + (long)scsw * 8;
  const int ldsoff = wv * 512;   // elements; + q*4096; lane*16B added by HW

  // read-side swizzle: chunk' = lk ^ ((row>>1)&3); row bits 1-2 come from l15 only.
  const int rdsw = (lk ^ ((l15 >> 1) & 3)) * 8;
  const int aoff0 = (wr * 128 + l15) * 32 + rdsw;   // + i*512 per 16-row step
  const int boff0 = (wcn * 64 + l15) * 32 + rdsw;   // + j*512

  f32x4 acc[8][4];
#pragma unroll
  for (int i = 0; i < 8; ++i)
#pragma unroll
    for (int j = 0; j < 4; ++j) acc[i][j] = (f32x4){0.f, 0.f, 0.f, 0.f};

  // prologue: stage tiles 0,1,2 into buffers 0,1,2
#pragma unroll
  for (int p = 0; p < 3; ++p) {
    const long kb = (long)p * 32;
#pragma unroll
    for (int q = 0; q < 2; ++q) {
      gload16(Ab + soff + q * (128L * K) + kb, &As[p][q * 4096 + ldsoff]);
      gload16(Bb + soff + q * (128L * K) + kb, &Bs[p][q * 4096 + ldsoff]);
    }
  }

  const int nt = K >> 5;
  for (int t = 0; t < nt; ++t) {
    const int cb = t & 3;
    if (t + 3 < nt) {
      const int pb = (t + 3) & 3;
      const long kb = (long)(t + 3) * 32;
#pragma unroll
      for (int q = 0; q < 2; ++q) {
        gload16(Ab + soff + q * (128L * K) + kb, &As[pb][q * 4096 + ldsoff]);
        gload16(Bb + soff + q * (128L * K) + kb, &Bs[pb][q * 4096 + ldsoff]);
      }
      asm volatile("s_waitcnt vmcnt(12)" ::: "memory");   // tile t landed; t+1..t+3 in flight
    } else if (t + 2 < nt) {
      asm volatile("s_waitcnt vmcnt(8)" ::: "memory");
    } else if (t + 1 < nt) {
      asm volatile("s_waitcnt vmcnt(4)" ::: "memory");
    } else {
      asm volatile("s_waitcnt vmcnt(0)" ::: "memory");
    }
    __builtin_amdgcn_s_barrier();
    __builtin_amdgcn_sched_barrier(0);

    // B fragments: 4 x ds_read_b128 (conflict-free via swizzle)
    short8v bfr[4];
#pragma unroll
    for (int j = 0; j < 4; ++j)
      bfr[j] = *(const short8v*)&Bs[cb][boff0 + j * 512];

#pragma unroll
    for (int ih = 0; ih < 4; ++ih) {
      short8v af0 = *(const short8v*)&As[cb][aoff0 + (ih * 2 + 0) * 512];
      short8v af1 = *(const short8v*)&As[cb][aoff0 + (ih * 2 + 1) * 512];
      __builtin_amdgcn_s_setprio(1);
#pragma unroll
      for (int j = 0; j < 4; ++j) {
        acc[ih * 2 + 0][j] = __builtin_amdgcn_mfma_f32_16x16x32_bf16(af0, bfr[j], acc[ih * 2 + 0][j], 0, 0, 0);
        acc[ih * 2 + 1][j] = __builtin_amdgcn_mfma_f32_16x16x32_bf16(af1, bfr[j], acc[ih * 2 + 1][j], 0, 0, 0);
      }
      __builtin_amdgcn_s_setprio(0);
    }
    __builtin_amdgcn_sched_barrier(0);
    __builtin_amdgcn_s_barrier();
  }

  const int row0 = bm * 256 + wr * 128;
  const int col0 = bn * 256 + wcn * 64;

  if constexpr (EPI == 1) {
    float* Cb = (float*)O0 + (long)bz * sC;
    const float g = gptr[0];
#pragma unroll
    for (int i = 0; i < 8; ++i)
#pragma unroll
      for (int j = 0; j < 4; ++j) {
        const int col = col0 + j * 16 + l15;
        const float tl = tailor[bz * 1024 + col];
#pragma unroll
        for (int r = 0; r < 4; ++r) {
          const int row = row0 + i * 16 + lk * 4 + r;
          const long idx = ((long)bz * 2048 + row) * 1024 + col;
          Cb[(long)row * 1024 + col] = b2f(xh[idx]) + g * ((Vsum[bz * 2048 + row] + acc[i][j][r]) * tl);
        }
      }
  } else if constexpr (EPI == 4) {
    unsigned short* Cb = (unsigned short*)O0 + (long)bz * sC;
#pragma unroll
    for (int i = 0; i < 8; ++i) {
#pragma unroll
      for (int j = 0; j < 4; ++j) {
        const int col = col0 + j * 16 + l15;
#pragma unroll
        for (int r = 0; r < 4; ++r) {
          const int row = row0 + i * 16 + lk * 4 + r;
          Cb[(long)row * 1024 + col] = f2b(acc[i][j][r]);
        }
      }
#pragma unroll
      for (int r = 0; r < 4; ++r) {
        float sm = acc[i][0][r] + acc[i][1][r] + acc[i][2][r] + acc[i][3][r];
        sm = red16(sm);
        if (l15 == 0) {
          const int row = row0 + i * 16 + lk * 4 + r;
          atomicAdd(&r4[(long)bz * 1024 + row], sm);
        }
      }
    }
  } else {  // EPI == 5: merged QKV
    const int seg = bn >> 2;             // 0=Q, 1=K, 2=V
    unsigned short* outp = seg == 0 ? (unsigned short*)O0
                        : seg == 1 ? (unsigned short*)O1 : (unsigned short*)O2;
    const int b = bm >> 3;               // batch (2048 rows per batch, 8 m-tiles)
    float bvj[4];
#pragma unroll
    for (int j = 0; j < 4; ++j) bvj[j] = bias[col0 + j * 16 + l15];
    const int colL0 = col0 & 1023;
#pragma unroll
    for (int i = 0; i < 8; ++i)
#pragma unroll
      for (int j = 0; j < 4; ++j) {
        const int colL = colL0 + j * 16 + l15;
#pragma unroll
        for (int r = 0; r < 4; ++r) {
          const int row = row0 + i * 16 + lk * 4 + r;
          outp[(long)row * 1024 + colL] = f2b(acc[i][j][r] + bvj[j]);
        }
      }
    if (seg < 2) {
      // per-column sumsq (and sum for Q) over this block's 256 rows
#pragma unroll
      for (int j = 0; j < 4; ++j) {
        const int colL = colL0 + j * 16 + l15;
        float ss = 0.f, sm = 0.f;
#pragma unroll
        for (int i = 0; i < 8; ++i)
#pragma unroll
          for (int r = 0; r < 4; ++r) {
            const float v = acc[i][j][r] + bvj[j];
            ss += v * v; sm += v;
          }
        ss = red4lk(ss);
        if (seg == 0) sm = red4lk(sm);
        if (lk == 0) {
          atomicAdd(&(seg == 0 ? r1 : r3)[(long)b * 1024 + colL], ss);
          if (seg == 0) atomicAdd(&r2[(long)b * 1024 + colL], sm);
        }
      }
    } else {
      // per-row sum over this block's 256 cols (V row-sums)
#pragma unroll
      for (int i = 0; i < 8; ++i)
#pragma unroll
        for (int r = 0; r < 4; ++r) {
          float sm = 0.f;
#pragma unroll
          for (int j = 0; j < 4; ++j) sm += acc[i][j][r] + bvj[j];
          sm = red16(sm);
          if (l15 == 0) {
            const int row = row0 + i * 16 + lk * 4 + r;
            atomicAdd(&r4[row], sm);
          }
        }
    }
  }
}

extern "C" void kernel_launch(void* const* d_in, const int* in_sizes, int n_in,
                              void* d_out, int out_size, void* d_ws, size_t ws_size,
                              hipStream_t stream) {
  (void)in_sizes; (void)n_in; (void)out_size;
  const float* x     = (const float*)d_in[0];
  const float* Wq    = (const float*)d_in[1];
  const float* bq    = (const float*)d_in[2];
  const float* Wk    = (const float*)d_in[3];
  const float* bk    = (const float*)d_in[4];
  const float* Wv    = (const float*)d_in[5];
  const float* bv    = (const float*)d_in[6];
  const float* gamma = (const float*)d_in[7];

  // B=16, C=2048, L=D=1024
  const long NE = 16L * 2048 * 1024;
  const long BUF = NE * 2;                    // bytes per bf16 tensor

  char* w = (char*)d_ws;
  unsigned short* Qh  = (unsigned short*)(w);            // later overlaid by S
  unsigned short* Kh  = (unsigned short*)(w + BUF);      // later overlaid by QT
  unsigned short* Vh  = (unsigned short*)(w + 2 * BUF);
  unsigned short* xh  = (unsigned short*)(w + 3 * BUF);  // live to the end
  unsigned short* KnT = (unsigned short*)(w + 4 * BUF);
  unsigned short* S   = Qh;
  unsigned short* QT  = Kh;
  size_t off = 5 * (size_t)BUF;
  unsigned short* Wqkvh = (unsigned short*)(w + off); off += 3 * 2097152;  // Wq|Wk|Wv contiguous
  char* accbase = w + off;
  float* pq     = (float*)(w + off); off += 65536;       // col sumsq of Q  (16x1024)
  float* qsum   = (float*)(w + off); off += 65536;       // col sum of Q
  float* pk     = (float*)(w + off); off += 65536;       // col sumsq of K
  float* Vsum   = (float*)(w + off); off += 131072;      // row sum of V    (16x2048)
  float* Srow   = (float*)(w + off); off += 65536;       // row sum of S    (16x1024)
  const size_t accbytes = (size_t)(w + off - accbase);
  float* invq   = (float*)(w + off); off += 65536;
  float* invk   = (float*)(w + off); off += 65536;
  float* tailor = (float*)(w + off); off += 65536;
  float* bqkv   = (float*)(w + off); off += 12288;
  if (ws_size < off) return;

  // 0) zero atomic accumulators
  hipMemsetAsync(accbase, 0, accbytes, stream);

  // 1) casts + bias concat
  k_f32_to_bf16<<<dim3((unsigned)(NE / 1024)), 256, 0, stream>>>(x, xh, NE);
  k_f32_to_bf16<<<dim3(1024), 256, 0, stream>>>(Wq, Wqkvh, 1048576);
  k_f32_to_bf16<<<dim3(1024), 256, 0, stream>>>(Wk, Wqkvh + 1048576, 1048576);
  k_f32_to_bf16<<<dim3(1024), 256, 0, stream>>>(Wv, Wqkvh + 2097152, 1048576);
  k_bias_cat<<<dim3(12), 256, 0, stream>>>(bq, bk, bv, bqkv);

  // 2) merged QKV GEMM: M=32768, N=3072, K=1024 + fused reductions
  k_g256<5><<<dim3(12, 128, 1), 512, 0, stream>>>(
      xh, Wqkvh, Qh, Kh, Vh, 1024, 0, 0, 0, bqkv,
      pq, qsum, pk, Vsum, nullptr, nullptr, nullptr, nullptr);

  // 3) inverse norms
  k_norms_fin<<<dim3(64), 256, 0, stream>>>(pq, pk, invq, invk);

  // 4) KnT = T(Kh)*invk   (before QT overlays Kh)
  k_transpose_scale<<<dim3(32, 16, 16), 256, 0, stream>>>(Kh, invk, KnT);

  // 5) QT = T(Qh)*invq    (overlays Kh)
  k_transpose_scale<<<dim3(32, 16, 16), 256, 0, stream>>>(Qh, invq, QT);

  // 6) S = QT x KnT^T per batch (M=N=1024, K=2048) + row sums — overlays Qh
  k_g256<4><<<dim3(4, 4, 16), 512, 0, stream>>>(
      QT, KnT, S, nullptr, nullptr, 2048, 1024L * 2048, 1024L * 2048, 1024L * 1024,
      nullptr, nullptr, nullptr, nullptr, Srow, nullptr, nullptr, nullptr, nullptr);

  // 7) tailor
  k_tailor_fin<<<dim3(64), 256, 0, stream>>>(Srow, invq, qsum, tailor);

  // 8) out = xh + gamma*(Vsum + V x S^T) * tailor   (M=2048/batch, N=1024, K=1024)
  k_g256<1><<<dim3(4, 8, 16), 512, 0, stream>>>(
      Vh, S, d_out, nullptr, nullptr, 1024, 2048L * 1024, 1024L * 1024, 2048L * 1024,
      nullptr, nullptr, nullptr, nullptr, nullptr, xh, Vsum, tailor, gamma);
}

// Round 7
// 599.233 us; speedup vs baseline: 1.0661x; 1.0661x over previous
//
#include <hip/hip_runtime.h>
#include <cstdint>

#define DEV static __device__ __forceinline__

typedef __attribute__((ext_vector_type(8))) short short8v;     // 8 x bf16 bits
typedef __attribute__((ext_vector_type(4))) float f32x4;
typedef __attribute__((ext_vector_type(4))) float fl4;
typedef __attribute__((ext_vector_type(4))) unsigned short us4;
typedef __attribute__((ext_vector_type(8))) unsigned short us8;

DEV float b2f(unsigned short u) {
  union { unsigned int i; float f; } c; c.i = ((unsigned int)u) << 16; return c.f;
}
DEV unsigned short f2b(float f) {   // RNE float -> bf16 bits
  union { float f; unsigned int i; } c; c.f = f;
  unsigned int u = c.i;
  u += 0x7fffu + ((u >> 16) & 1u);
  return (unsigned short)(u >> 16);
}

DEV void gload16(const void* g, void* l) {  // async global->LDS, 16B/lane
  __builtin_amdgcn_global_load_lds(
      (const __attribute__((address_space(1))) unsigned int*)g,
      (__attribute__((address_space(3))) unsigned int*)l, 16, 0, 0);
}

DEV float red16(float v) {  // reduce across 16 lanes sharing lk (xor low 4 bits)
  v += __shfl_xor(v, 1); v += __shfl_xor(v, 2);
  v += __shfl_xor(v, 4); v += __shfl_xor(v, 8);
  return v;
}
DEV float red4lk(float v) { // reduce across the 4 lk groups (xor bits 4,5)
  v += __shfl_xor(v, 16); v += __shfl_xor(v, 32);
  return v;
}

// ---------------- elementwise f32 -> bf16 ----------------
__global__ __launch_bounds__(256) void k_f32_to_bf16(const float* __restrict__ src,
                                                     unsigned short* __restrict__ dst, long n) {
  long i = ((long)blockIdx.x * 256 + threadIdx.x) * 4;
  if (i >= n) return;
  fl4 v = *(const fl4*)(src + i);
  us4 o;
  o[0] = f2b(v[0]); o[1] = f2b(v[1]); o[2] = f2b(v[2]); o[3] = f2b(v[3]);
  *(us4*)(dst + i) = o;
}

// ---------------- concat biases into 3072-float buffer ----------------
__global__ __launch_bounds__(256) void k_bias_cat(const float* __restrict__ bq,
                                                  const float* __restrict__ bk,
                                                  const float* __restrict__ bv,
                                                  float* __restrict__ o) {
  const int t = blockIdx.x * 256 + threadIdx.x;   // 3072
  o[t] = t < 1024 ? bq[t] : (t < 2048 ? bk[t - 1024] : bv[t - 2048]);
}

// ---------------- finalize inverse norms ----------------
__global__ __launch_bounds__(256) void k_norms_fin(const float* __restrict__ pq,
                                                   const float* __restrict__ pk,
                                                   float* __restrict__ invq, float* __restrict__ invk) {
  const int gid = blockIdx.x * 256 + threadIdx.x;   // 16384
  invq[gid] = rsqrtf(pq[gid]);
  invk[gid] = rsqrtf(pk[gid]);
}

// ---------------- finalize tailor: 1/(L + rowsum(S) + eps*invq*colsum(Q)) ----------------
__global__ __launch_bounds__(256) void k_tailor_fin(const float* __restrict__ Srow,
                                                    const float* __restrict__ invq,
                                                    const float* __restrict__ qsum,
                                                    float* __restrict__ tailor) {
  const int gid = blockIdx.x * 256 + threadIdx.x;   // 16384
  tailor[gid] = 1.0f / (1024.0f + Srow[gid] + 1e-6f * invq[gid] * qsum[gid]);
}

// ---------------- transpose+scale: (B,2048,1024) -> (B,1024,2048), dst row j scaled ----------------
__global__ __launch_bounds__(256) void k_transpose_scale(const unsigned short* __restrict__ Q,
                                                         const float* __restrict__ scale,
                                                         unsigned short* __restrict__ QT) {
  __shared__ unsigned short tile[64][68];
  const int c0 = blockIdx.x * 64, n0 = blockIdx.y * 64, b = blockIdx.z;
  const int jr = (threadIdx.x & 15) * 4;
  const int ir = threadIdx.x >> 4;
  const unsigned short* src = Q + ((long)b * 2048 + c0) * 1024 + n0;
#pragma unroll
  for (int p = 0; p < 4; ++p) {
    int i = ir + p * 16;
    *(us4*)&tile[i][jr] = *(const us4*)(src + (long)i * 1024 + jr);
  }
  __syncthreads();
  unsigned short* dst = QT + ((long)b * 1024 + n0) * 2048 + c0;
#pragma unroll
  for (int p = 0; p < 4; ++p) {
    int j = ir + p * 16;
    const float s = scale[b * 1024 + n0 + j];
    us4 o;
    o[0] = f2b(b2f(tile[jr + 0][j]) * s);
    o[1] = f2b(b2f(tile[jr + 1][j]) * s);
    o[2] = f2b(b2f(tile[jr + 2][j]) * s);
    o[3] = f2b(b2f(tile[jr + 3][j]) * s);
    *(us4*)(dst + (long)j * 2048 + jr) = o;
  }
}

// ---------------- 256x256 NT GEMM, BK=64, 8 waves (2Mx4N), 4-phase/K-tile schedule ----------
// Per K-tile: 4 phases, each {stage-issue || ds_read subtile -> 16 MFMA (one C-quadrant)
// -> s_barrier}. Wave (wr,wcn) reads ONLY its A-half (wr) and B-quarter (wcn), so phase
// ds_reads are 0-16 per wave; per-wave lgkm counters (compiler-inserted) let MFMA overlap
// in-flight reads; barriers keep waves phase-aligned so CU-wide LDS and MFMA bursts stagger.
// Tile t+1's 8 gloads are issued at phases q0/q1 of tile t -> >=3 phases of age before the
// single vmcnt(0) at the next tile top (pre-aged wait, no fresh drain).
// LDS chunk-swizzle: logical (row, chunk c in [0,8)) stored at physical chunk c^(row&7);
// stage pre-swizzles the GLOBAL source chunk (LDS dest stays lane-linear), reads apply the
// same XOR (reduces to l15-only on the read side).
// C[m][n] = sum_k A[m][k] * Bt[n][k]; out col-stride fixed 1024.
// EPI 1: final fused fp32 epilogue.  EPI 4: bf16 out + per-row atomic sum.  EPI 5: merged QKV.
template<int EPI>
__global__ __launch_bounds__(512)
void k_g256(const unsigned short* __restrict__ A,
            const unsigned short* __restrict__ Bt,
            void* __restrict__ O0, void* __restrict__ O1, void* __restrict__ O2,
            int K, long sA, long sB, long sC,
            const float* __restrict__ bias,
            float* __restrict__ r1, float* __restrict__ r2,
            float* __restrict__ r3, float* __restrict__ r4,
            const unsigned short* __restrict__ xh,
            const float* __restrict__ Vsum,
            const float* __restrict__ tailor,
            const float* __restrict__ gptr) {
  __shared__ __align__(16) unsigned short As[2][16384];   // 2 x 256x64 bf16 = 64 KiB
  __shared__ __align__(16) unsigned short Bs[2][16384];   // 64 KiB  (total 128 KiB)

  const int tid = threadIdx.x;
  const int wv = tid >> 6, lane = tid & 63;
  const int wr = wv >> 2, wcn = wv & 3;          // 2 x 4 wave grid
  const int l15 = lane & 15, lk = lane >> 4;

  // XCD-bijective swizzle over (x,y); nwg % 8 == 0 for all grids used
  const int nx = gridDim.x;
  const int nwg = nx * gridDim.y;
  const int lin = blockIdx.y * nx + blockIdx.x;
  const int cpx = nwg >> 3;
  const int wg = (lin & 7) * cpx + (lin >> 3);
  const int bn = wg % nx;
  const int bm = wg / nx;
  const int bz = blockIdx.z;

  const unsigned short* Ab = A + (long)bz * sA + (long)bm * 256 * K;
  const unsigned short* Bb = Bt + (long)bz * sB + (long)bn * 256 * K;

  // staging: quarter Q covers rows [64Q,64Q+64) x 64 k-cols (8 KiB = 1 gload16/wave).
  // thread tid handles row = 64Q + (tid>>3), physical chunk tid&7; pre-swizzled global
  // chunk = (tid&7) ^ (row&7). LDS base (wave-uniform): Q*4096 + wv*512 elements.
  const int srow = tid >> 3;
  const int cg = (tid & 7) ^ (srow & 7);
  const long gOff = (long)srow * K + (long)cg * 8;   // + 64*Q*K + t*64
  const int ldsb = wv * 512;                         // + Q*4096

  // read side: frag (row r, k-step ks): elem off = r*64 + ((ks*4+lk)^(r&7))*8; r&7 == l15&7.
  const int sw0 = ((lk) ^ (l15 & 7)) * 8;
  const int sw1 = ((4 + lk) ^ (l15 & 7)) * 8;
  const int abase = (wr * 128 + l15) * 64;   // + i*1024
  const int bbase = (wcn * 64 + l15) * 64;   // + j*1024

  f32x4 acc[8][4];
#pragma unroll
  for (int i = 0; i < 8; ++i)
#pragma unroll
    for (int j = 0; j < 4; ++j) acc[i][j] = (f32x4){0.f, 0.f, 0.f, 0.f};

  // prologue: stage tile 0 into buf 0 (8 quarters)
#pragma unroll
  for (int Q = 0; Q < 4; ++Q) {
    gload16(Ab + (long)(Q * 64) * K + gOff, &As[0][Q * 4096 + ldsb]);
    gload16(Bb + (long)(Q * 64) * K + gOff, &Bs[0][Q * 4096 + ldsb]);
  }

  short8v Afr[4][2], Bfr[4][2];
  const int NT = K >> 6;
  for (int t = 0; t < NT; ++t) {
    const int cb = t & 1;
    asm volatile("s_waitcnt vmcnt(0)" ::: "memory");   // own tile-t loads landed (pre-aged)
    __builtin_amdgcn_s_barrier();                      // => all waves' slices landed
    __builtin_amdgcn_sched_barrier(0);

    // ---- q0: stage A/B quarters 0,1 of t+1; read all B (8) + A mh0 (8); MFMA mh0 x nh0
    if (t + 1 < NT) {
      const long kb = (long)(t + 1) * 64;
      gload16(Ab + kb + gOff,              &As[cb ^ 1][ldsb]);
      gload16(Ab + kb + gOff + 64L * K,    &As[cb ^ 1][4096 + ldsb]);
      gload16(Bb + kb + gOff,              &Bs[cb ^ 1][ldsb]);
      gload16(Bb + kb + gOff + 64L * K,    &Bs[cb ^ 1][4096 + ldsb]);
    }
#pragma unroll
    for (int j = 0; j < 4; ++j) {
      Bfr[j][0] = *(const short8v*)&Bs[cb][bbase + j * 1024 + sw0];
      Bfr[j][1] = *(const short8v*)&Bs[cb][bbase + j * 1024 + sw1];
    }
#pragma unroll
    for (int i = 0; i < 4; ++i) {
      Afr[i][0] = *(const short8v*)&As[cb][abase + i * 1024 + sw0];
      Afr[i][1] = *(const short8v*)&As[cb][abase + i * 1024 + sw1];
    }
    __builtin_amdgcn_s_setprio(1);
#pragma unroll
    for (int i = 0; i < 4; ++i)
#pragma unroll
      for (int j = 0; j < 2; ++j) {
        acc[i][j] = __builtin_amdgcn_mfma_f32_16x16x32_bf16(Afr[i][0], Bfr[j][0], acc[i][j], 0, 0, 0);
        acc[i][j] = __builtin_amdgcn_mfma_f32_16x16x32_bf16(Afr[i][1], Bfr[j][1], acc[i][j], 0, 0, 0);
      }
    __builtin_amdgcn_s_setprio(0);
    __builtin_amdgcn_s_barrier();
    __builtin_amdgcn_sched_barrier(0);

    // ---- q1: stage quarters 2,3 of t+1; MFMA mh0 x nh1 (all-reg)
    if (t + 1 < NT) {
      const long kb = (long)(t + 1) * 64;
      gload16(Ab + kb + gOff + 128L * K,   &As[cb ^ 1][8192 + ldsb]);
      gload16(Ab + kb + gOff + 192L * K,   &As[cb ^ 1][12288 + ldsb]);
      gload16(Bb + kb + gOff + 128L * K,   &Bs[cb ^ 1][8192 + ldsb]);
      gload16(Bb + kb + gOff + 192L * K,   &Bs[cb ^ 1][12288 + ldsb]);
    }
    __builtin_amdgcn_s_setprio(1);
#pragma unroll
    for (int i = 0; i < 4; ++i)
#pragma unroll
      for (int j = 2; j < 4; ++j) {
        acc[i][j] = __builtin_amdgcn_mfma_f32_16x16x32_bf16(Afr[i][0], Bfr[j][0], acc[i][j], 0, 0, 0);
        acc[i][j] = __builtin_amdgcn_mfma_f32_16x16x32_bf16(Afr[i][1], Bfr[j][1], acc[i][j], 0, 0, 0);
      }
    __builtin_amdgcn_s_setprio(0);
    __builtin_amdgcn_s_barrier();
    __builtin_amdgcn_sched_barrier(0);

    // ---- q2: read A mh1 (8); MFMA mh1 x nh0
#pragma unroll
    for (int i = 0; i < 4; ++i) {
      Afr[i][0] = *(const short8v*)&As[cb][abase + (i + 4) * 1024 + sw0];
      Afr[i][1] = *(const short8v*)&As[cb][abase + (i + 4) * 1024 + sw1];
    }
    __builtin_amdgcn_s_setprio(1);
#pragma unroll
    for (int i = 0; i < 4; ++i)
#pragma unroll
      for (int j = 0; j < 2; ++j) {
        acc[i + 4][j] = __builtin_amdgcn_mfma_f32_16x16x32_bf16(Afr[i][0], Bfr[j][0], acc[i + 4][j], 0, 0, 0);
        acc[i + 4][j] = __builtin_amdgcn_mfma_f32_16x16x32_bf16(Afr[i][1], Bfr[j][1], acc[i + 4][j], 0, 0, 0);
      }
    __builtin_amdgcn_s_setprio(0);
    __builtin_amdgcn_s_barrier();
    __builtin_amdgcn_sched_barrier(0);

    // ---- q3: MFMA mh1 x nh1 (all-reg); no trailing barrier (next tile top has one)
    __builtin_amdgcn_s_setprio(1);
#pragma unroll
    for (int i = 0; i < 4; ++i)
#pragma unroll
      for (int j = 2; j < 4; ++j) {
        acc[i + 4][j] = __builtin_amdgcn_mfma_f32_16x16x32_bf16(Afr[i][0], Bfr[j][0], acc[i + 4][j], 0, 0, 0);
        acc[i + 4][j] = __builtin_amdgcn_mfma_f32_16x16x32_bf16(Afr[i][1], Bfr[j][1], acc[i + 4][j], 0, 0, 0);
      }
    __builtin_amdgcn_s_setprio(0);
  }

  const int row0 = bm * 256 + wr * 128;
  const int col0 = bn * 256 + wcn * 64;

  if constexpr (EPI == 1) {
    float* Cb = (float*)O0 + (long)bz * sC;
    const float g = gptr[0];
#pragma unroll
    for (int i = 0; i < 8; ++i)
#pragma unroll
      for (int j = 0; j < 4; ++j) {
        const int col = col0 + j * 16 + l15;
        const float tl = tailor[bz * 1024 + col];
#pragma unroll
        for (int r = 0; r < 4; ++r) {
          const int row = row0 + i * 16 + lk * 4 + r;
          const long idx = ((long)bz * 2048 + row) * 1024 + col;
          Cb[(long)row * 1024 + col] = b2f(xh[idx]) + g * ((Vsum[bz * 2048 + row] + acc[i][j][r]) * tl);
        }
      }
  } else if constexpr (EPI == 4) {
    unsigned short* Cb = (unsigned short*)O0 + (long)bz * sC;
#pragma unroll
    for (int i = 0; i < 8; ++i) {
#pragma unroll
      for (int j = 0; j < 4; ++j) {
        const int col = col0 + j * 16 + l15;
#pragma unroll
        for (int r = 0; r < 4; ++r) {
          const int row = row0 + i * 16 + lk * 4 + r;
          Cb[(long)row * 1024 + col] = f2b(acc[i][j][r]);
        }
      }
#pragma unroll
      for (int r = 0; r < 4; ++r) {
        float sm = acc[i][0][r] + acc[i][1][r] + acc[i][2][r] + acc[i][3][r];
        sm = red16(sm);
        if (l15 == 0) {
          const int row = row0 + i * 16 + lk * 4 + r;
          atomicAdd(&r4[(long)bz * 1024 + row], sm);
        }
      }
    }
  } else {  // EPI == 5: merged QKV
    const int seg = bn >> 2;             // 0=Q, 1=K, 2=V
    unsigned short* outp = seg == 0 ? (unsigned short*)O0
                        : seg == 1 ? (unsigned short*)O1 : (unsigned short*)O2;
    const int b = bm >> 3;               // batch (2048 rows per batch, 8 m-tiles)
    float bvj[4];
#pragma unroll
    for (int j = 0; j < 4; ++j) bvj[j] = bias[col0 + j * 16 + l15];
    const int colL0 = col0 & 1023;
#pragma unroll
    for (int i = 0; i < 8; ++i)
#pragma unroll
      for (int j = 0; j < 4; ++j) {
        const int colL = colL0 + j * 16 + l15;
#pragma unroll
        for (int r = 0; r < 4; ++r) {
          const int row = row0 + i * 16 + lk * 4 + r;
          outp[(long)row * 1024 + colL] = f2b(acc[i][j][r] + bvj[j]);
        }
      }
    if (seg < 2) {
      // per-column sumsq (and sum for Q) over this block's 256 rows
#pragma unroll
      for (int j = 0; j < 4; ++j) {
        const int colL = colL0 + j * 16 + l15;
        float ss = 0.f, sm = 0.f;
#pragma unroll
        for (int i = 0; i < 8; ++i)
#pragma unroll
          for (int r = 0; r < 4; ++r) {
            const float v = acc[i][j][r] + bvj[j];
            ss += v * v; sm += v;
          }
        ss = red4lk(ss);
        if (seg == 0) sm = red4lk(sm);
        if (lk == 0) {
          atomicAdd(&(seg == 0 ? r1 : r3)[(long)b * 1024 + colL], ss);
          if (seg == 0) atomicAdd(&r2[(long)b * 1024 + colL], sm);
        }
      }
    } else {
      // per-row sum over this block's 256 cols (V row-sums)
#pragma unroll
      for (int i = 0; i < 8; ++i)
#pragma unroll
        for (int r = 0; r < 4; ++r) {
          float sm = 0.f;
#pragma unroll
          for (int j = 0; j < 4; ++j) sm += acc[i][j][r] + bvj[j];
          sm = red16(sm);
          if (l15 == 0) {
            const int row = row0 + i * 16 + lk * 4 + r;
            atomicAdd(&r4[row], sm);
          }
        }
    }
  }
}

extern "C" void kernel_launch(void* const* d_in, const int* in_sizes, int n_in,
                              void* d_out, int out_size, void* d_ws, size_t ws_size,
                              hipStream_t stream) {
  (void)in_sizes; (void)n_in; (void)out_size;
  const float* x     = (const float*)d_in[0];
  const float* Wq    = (const float*)d_in[1];
  const float* bq    = (const float*)d_in[2];
  const float* Wk    = (const float*)d_in[3];
  const float* bk    = (const float*)d_in[4];
  const float* Wv    = (const float*)d_in[5];
  const float* bv    = (const float*)d_in[6];
  const float* gamma = (const float*)d_in[7];

  // B=16, C=2048, L=D=1024
  const long NE = 16L * 2048 * 1024;
  const long BUF = NE * 2;                    // bytes per bf16 tensor

  char* w = (char*)d_ws;
  unsigned short* Qh  = (unsigned short*)(w);            // later overlaid by S
  unsigned short* Kh  = (unsigned short*)(w + BUF);      // later overlaid by QT
  unsigned short* Vh  = (unsigned short*)(w + 2 * BUF);
  unsigned short* xh  = (unsigned short*)(w + 3 * BUF);  // live to the end
  unsigned short* KnT = (unsigned short*)(w + 4 * BUF);
  unsigned short* S   = Qh;
  unsigned short* QT  = Kh;
  size_t off = 5 * (size_t)BUF;
  unsigned short* Wqkvh = (unsigned short*)(w + off); off += 3 * 2097152;  // Wq|Wk|Wv contiguous
  char* accbase = w + off;
  float* pq     = (float*)(w + off); off += 65536;       // col sumsq of Q  (16x1024)
  float* qsum   = (float*)(w + off); off += 65536;       // col sum of Q
  float* pk     = (float*)(w + off); off += 65536;       // col sumsq of K
  float* Vsum   = (float*)(w + off); off += 131072;      // row sum of V    (16x2048)
  float* Srow   = (float*)(w + off); off += 65536;       // row sum of S    (16x1024)
  const size_t accbytes = (size_t)(w + off - accbase);
  float* invq   = (float*)(w + off); off += 65536;
  float* invk   = (float*)(w + off); off += 65536;
  float* tailor = (float*)(w + off); off += 65536;
  float* bqkv   = (float*)(w + off); off += 12288;
  if (ws_size < off) return;

  // 0) zero atomic accumulators
  hipMemsetAsync(accbase, 0, accbytes, stream);

  // 1) casts + bias concat
  k_f32_to_bf16<<<dim3((unsigned)(NE / 1024)), 256, 0, stream>>>(x, xh, NE);
  k_f32_to_bf16<<<dim3(1024), 256, 0, stream>>>(Wq, Wqkvh, 1048576);
  k_f32_to_bf16<<<dim3(1024), 256, 0, stream>>>(Wk, Wqkvh + 1048576, 1048576);
  k_f32_to_bf16<<<dim3(1024), 256, 0, stream>>>(Wv, Wqkvh + 2097152, 1048576);
  k_bias_cat<<<dim3(12), 256, 0, stream>>>(bq, bk, bv, bqkv);

  // 2) merged QKV GEMM: M=32768, N=3072, K=1024 + fused reductions
  k_g256<5><<<dim3(12, 128, 1), 512, 0, stream>>>(
      xh, Wqkvh, Qh, Kh, Vh, 1024, 0, 0, 0, bqkv,
      pq, qsum, pk, Vsum, nullptr, nullptr, nullptr, nullptr);

  // 3) inverse norms
  k_norms_fin<<<dim3(64), 256, 0, stream>>>(pq, pk, invq, invk);

  // 4) KnT = T(Kh)*invk   (before QT overlays Kh)
  k_transpose_scale<<<dim3(32, 16, 16), 256, 0, stream>>>(Kh, invk, KnT);

  // 5) QT = T(Qh)*invq    (overlays Kh)
  k_transpose_scale<<<dim3(32, 16, 16), 256, 0, stream>>>(Qh, invq, QT);

  // 6) S = QT x KnT^T per batch (M=N=1024, K=2048) + row sums — overlays Qh
  k_g256<4><<<dim3(4, 4, 16), 512, 0, stream>>>(
      QT, KnT, S, nullptr, nullptr, 2048, 1024L * 2048, 1024L * 2048, 1024L * 1024,
      nullptr, nullptr, nullptr, nullptr, Srow, nullptr, nullptr, nullptr, nullptr);

  // 7) tailor
  k_tailor_fin<<<dim3(64), 256, 0, stream>>>(Srow, invq, qsum, tailor);

  // 8) out = xh + gamma*(Vsum + V x S^T) * tailor   (M=2048/batch, N=1024, K=1024)
  k_g256<1><<<dim3(4, 8, 16), 512, 0, stream>>>(
      Vh, S, d_out, nullptr, nullptr, 1024, 2048L * 1024, 1024L * 1024, 2048L * 1024,
      nullptr, nullptr, nullptr, nullptr, nullptr, xh, Vsum, tailor, gamma);
}

// Round 8
// 559.441 us; speedup vs baseline: 1.1420x; 1.0711x over previous
//
#include <hip/hip_runtime.h>
#include <cstdint>

#define DEV static __device__ __forceinline__

typedef __attribute__((ext_vector_type(8))) short short8v;     // 8 x bf16 bits
typedef __attribute__((ext_vector_type(4))) float f32x4;
typedef __attribute__((ext_vector_type(4))) float fl4;
typedef __attribute__((ext_vector_type(4))) unsigned short us4;
typedef __attribute__((ext_vector_type(8))) unsigned short us8;

DEV float b2f(unsigned short u) {
  union { unsigned int i; float f; } c; c.i = ((unsigned int)u) << 16; return c.f;
}
DEV unsigned short f2b(float f) {   // RNE float -> bf16 bits
  union { float f; unsigned int i; } c; c.f = f;
  unsigned int u = c.i;
  u += 0x7fffu + ((u >> 16) & 1u);
  return (unsigned short)(u >> 16);
}

DEV void gload16(const void* g, void* l) {  // async global->LDS, 16B/lane
  __builtin_amdgcn_global_load_lds(
      (const __attribute__((address_space(1))) unsigned int*)g,
      (__attribute__((address_space(3))) unsigned int*)l, 16, 0, 0);
}

DEV float red16(float v) {  // reduce across 16 lanes sharing lk (xor low 4 bits)
  v += __shfl_xor(v, 1); v += __shfl_xor(v, 2);
  v += __shfl_xor(v, 4); v += __shfl_xor(v, 8);
  return v;
}
DEV float red4lk(float v) { // reduce across the 4 lk groups (xor bits 4,5)
  v += __shfl_xor(v, 16); v += __shfl_xor(v, 32);
  return v;
}

// ---------------- elementwise f32 -> bf16 ----------------
__global__ __launch_bounds__(256) void k_f32_to_bf16(const float* __restrict__ src,
                                                     unsigned short* __restrict__ dst, long n) {
  long i = ((long)blockIdx.x * 256 + threadIdx.x) * 4;
  if (i >= n) return;
  fl4 v = *(const fl4*)(src + i);
  us4 o;
  o[0] = f2b(v[0]); o[1] = f2b(v[1]); o[2] = f2b(v[2]); o[3] = f2b(v[3]);
  *(us4*)(dst + i) = o;
}

// ---------------- concat biases into 3072-float buffer ----------------
__global__ __launch_bounds__(256) void k_bias_cat(const float* __restrict__ bq,
                                                  const float* __restrict__ bk,
                                                  const float* __restrict__ bv,
                                                  float* __restrict__ o) {
  const int t = blockIdx.x * 256 + threadIdx.x;   // 3072
  o[t] = t < 1024 ? bq[t] : (t < 2048 ? bk[t - 1024] : bv[t - 2048]);
}

// ---------------- finalize inverse norms ----------------
__global__ __launch_bounds__(256) void k_norms_fin(const float* __restrict__ pq,
                                                   const float* __restrict__ pk,
                                                   float* __restrict__ invq, float* __restrict__ invk) {
  const int gid = blockIdx.x * 256 + threadIdx.x;   // 16384
  invq[gid] = rsqrtf(pq[gid]);
  invk[gid] = rsqrtf(pk[gid]);
}

// ---------------- finalize tailor: 1/(L + rowsum(S) + eps*invq*colsum(Q)) ----------------
__global__ __launch_bounds__(256) void k_tailor_fin(const float* __restrict__ Srow,
                                                    const float* __restrict__ invq,
                                                    const float* __restrict__ qsum,
                                                    float* __restrict__ tailor) {
  const int gid = blockIdx.x * 256 + threadIdx.x;   // 16384
  tailor[gid] = 1.0f / (1024.0f + Srow[gid] + 1e-6f * invq[gid] * qsum[gid]);
}

// ---------------- transpose+scale: (B,2048,1024) -> (B,1024,2048), dst row j scaled ----------------
__global__ __launch_bounds__(256) void k_transpose_scale(const unsigned short* __restrict__ Q,
                                                         const float* __restrict__ scale,
                                                         unsigned short* __restrict__ QT) {
  __shared__ unsigned short tile[64][68];
  const int c0 = blockIdx.x * 64, n0 = blockIdx.y * 64, b = blockIdx.z;
  const int jr = (threadIdx.x & 15) * 4;
  const int ir = threadIdx.x >> 4;
  const unsigned short* src = Q + ((long)b * 2048 + c0) * 1024 + n0;
#pragma unroll
  for (int p = 0; p < 4; ++p) {
    int i = ir + p * 16;
    *(us4*)&tile[i][jr] = *(const us4*)(src + (long)i * 1024 + jr);
  }
  __syncthreads();
  unsigned short* dst = QT + ((long)b * 1024 + n0) * 2048 + c0;
#pragma unroll
  for (int p = 0; p < 4; ++p) {
    int j = ir + p * 16;
    const float s = scale[b * 1024 + n0 + j];
    us4 o;
    o[0] = f2b(b2f(tile[jr + 0][j]) * s);
    o[1] = f2b(b2f(tile[jr + 1][j]) * s);
    o[2] = f2b(b2f(tile[jr + 2][j]) * s);
    o[3] = f2b(b2f(tile[jr + 3][j]) * s);
    *(us4*)(dst + (long)j * 2048 + jr) = o;
  }
}

// ---------------- 256x256 NT GEMM, BK=32, 8 waves (2Mx4N), deep pipelined 2-phase/tile ----
// Per K-tile t (2 phases of 16 MFMA):
//   top: s_waitcnt vmcnt(4)  [tile t+1 landed, t+2 in flight — NEVER drain to 0] + barrier
//   phA: stage tile t+3 (4 gloads) || ds_read Ah1(t)->An || MFMA Q0 on (Ac,Bc) [in regs]
//   phB: ds_read B(t+1)->Bn, Ah0(t+1)->Ac || MFMA Q1 on (An,Bc)
// Every MFMA cluster uses fragments read ONE PHASE EARLIER (reads execute under MFMA);
// compiler inserts the counted lgkm waits at first use. 4 LDS buffers (128 KiB).
// LDS chunk-swizzle (verified conflict-free): logical (row, chunk c in [0,4)) stored at
// physical chunk c ^ ((row>>1)&3); stage pre-swizzles the GLOBAL source chunk.
// C[m][n] = sum_k A[m][k] * Bt[n][k]; out col-stride fixed 1024.
// EPI 1: final fused fp32 epilogue.  EPI 4: bf16 out + per-row atomic sum.  EPI 5: merged QKV.
template<int EPI>
__global__ __launch_bounds__(512)
void k_g256(const unsigned short* __restrict__ A,
            const unsigned short* __restrict__ Bt,
            void* __restrict__ O0, void* __restrict__ O1, void* __restrict__ O2,
            int K, long sA, long sB, long sC,
            const float* __restrict__ bias,
            float* __restrict__ r1, float* __restrict__ r2,
            float* __restrict__ r3, float* __restrict__ r4,
            const unsigned short* __restrict__ xh,
            const float* __restrict__ Vsum,
            const float* __restrict__ tailor,
            const float* __restrict__ gptr) {
  __shared__ __align__(16) unsigned short As[4][8192];   // 4 x 256x32 bf16 = 64 KiB
  __shared__ __align__(16) unsigned short Bs[4][8192];   // 64 KiB  (total 128 KiB)

  const int tid = threadIdx.x;
  const int wv = tid >> 6, lane = tid & 63;
  const int wr = wv >> 2, wcn = wv & 3;          // 2 x 4 wave grid
  const int l15 = lane & 15, lk = lane >> 4;

  // XCD-bijective swizzle over (x,y); nwg % 8 == 0 for all grids used
  const int nx = gridDim.x;
  const int nwg = nx * gridDim.y;
  const int lin = blockIdx.y * nx + blockIdx.x;
  const int cpx = nwg >> 3;
  const int wg = (lin & 7) * cpx + (lin >> 3);
  const int bn = wg % nx;
  const int bm = wg / nx;
  const int bz = blockIdx.z;

  const unsigned short* Ab = A + (long)bz * sA + (long)bm * 256 * K;
  const unsigned short* Bb = Bt + (long)bz * sB + (long)bn * 256 * K;

  // staging: thread tid covers row tid>>2 (gload q adds 128), physical chunk tid&3,
  // pre-swizzled global chunk = (tid&3) ^ ((row>>1)&3) = (tid&3) ^ ((tid>>3)&3).
  const int scsw = (tid & 3) ^ ((tid >> 3) & 3);
  const long gOff = (long)(tid >> 2) * K + (long)scsw * 8;   // + 128*q*K + t*32
  const int ldsb = wv * 512;                                  // + q*4096

  // read-side swizzle: chunk' = lk ^ ((row>>1)&3); row bits 1-2 come from l15 only.
  const int rdsw = (lk ^ ((l15 >> 1) & 3)) * 8;
  const int abase = (wr * 128 + l15) * 32;   // + i*512
  const int bbase = (wcn * 64 + l15) * 32;   // + j*512

  f32x4 acc[8][4];
#pragma unroll
  for (int i = 0; i < 8; ++i)
#pragma unroll
    for (int j = 0; j < 4; ++j) acc[i][j] = (f32x4){0.f, 0.f, 0.f, 0.f};

  // prologue: stage tiles 0,1,2 into buffers 0,1,2
#pragma unroll
  for (int p = 0; p < 3; ++p) {
    const long kb = (long)p * 32;
    gload16(Ab + kb + gOff,            &As[p][ldsb]);
    gload16(Ab + kb + gOff + 128L * K, &As[p][4096 + ldsb]);
    gload16(Bb + kb + gOff,            &Bs[p][ldsb]);
    gload16(Bb + kb + gOff + 128L * K, &Bs[p][4096 + ldsb]);
  }
  asm volatile("s_waitcnt vmcnt(8)" ::: "memory");   // tile 0 landed (1,2 in flight)
  __builtin_amdgcn_s_barrier();

  short8v Ac[4], An[4], Bc[4], Bn[4];
  // preload tile 0 fragments: B + A-half0
#pragma unroll
  for (int j = 0; j < 4; ++j) Bc[j] = *(const short8v*)&Bs[0][bbase + j * 512 + rdsw];
#pragma unroll
  for (int i = 0; i < 4; ++i) Ac[i] = *(const short8v*)&As[0][abase + i * 512 + rdsw];

  const int NT = K >> 5;

#define GEMM_TILE(T, BC, BN)                                                         \
  {                                                                                  \
    const int cb = (T) & 3;                                                          \
    if ((T) < NT - 2) { asm volatile("s_waitcnt vmcnt(4)" ::: "memory"); }           \
    else              { asm volatile("s_waitcnt vmcnt(0)" ::: "memory"); }           \
    __builtin_amdgcn_s_barrier();                                                    \
    __builtin_amdgcn_sched_barrier(0);                                               \
    if ((T) + 3 < NT) {                                                              \
      const int pb = ((T) + 3) & 3;                                                  \
      const long kb = (long)((T) + 3) * 32;                                          \
      gload16(Ab + kb + gOff,            &As[pb][ldsb]);                             \
      gload16(Ab + kb + gOff + 128L * K, &As[pb][4096 + ldsb]);                      \
      gload16(Bb + kb + gOff,            &Bs[pb][ldsb]);                             \
      gload16(Bb + kb + gOff + 128L * K, &Bs[pb][4096 + ldsb]);                      \
    }                                                                                \
    _Pragma("unroll")                                                                \
    for (int i = 0; i < 4; ++i)                                                      \
      An[i] = *(const short8v*)&As[cb][abase + (i + 4) * 512 + rdsw];                \
    __builtin_amdgcn_s_setprio(1);                                                   \
    _Pragma("unroll")                                                                \
    for (int i = 0; i < 4; ++i)                                                      \
      _Pragma("unroll")                                                              \
      for (int j = 0; j < 4; ++j)                                                    \
        acc[i][j] = __builtin_amdgcn_mfma_f32_16x16x32_bf16(Ac[i], BC[j], acc[i][j], 0, 0, 0); \
    __builtin_amdgcn_s_setprio(0);                                                   \
    __builtin_amdgcn_s_barrier();                                                    \
    __builtin_amdgcn_sched_barrier(0);                                               \
    if ((T) + 1 < NT) {                                                              \
      const int nb2 = ((T) + 1) & 3;                                                 \
      _Pragma("unroll")                                                              \
      for (int j = 0; j < 4; ++j)                                                    \
        BN[j] = *(const short8v*)&Bs[nb2][bbase + j * 512 + rdsw];                   \
      _Pragma("unroll")                                                              \
      for (int i = 0; i < 4; ++i)                                                    \
        Ac[i] = *(const short8v*)&As[nb2][abase + i * 512 + rdsw];                   \
    }                                                                                \
    __builtin_amdgcn_s_setprio(1);                                                   \
    _Pragma("unroll")                                                                \
    for (int i = 0; i < 4; ++i)                                                      \
      _Pragma("unroll")                                                              \
      for (int j = 0; j < 4; ++j)                                                    \
        acc[i + 4][j] = __builtin_amdgcn_mfma_f32_16x16x32_bf16(An[i], BC[j], acc[i + 4][j], 0, 0, 0); \
    __builtin_amdgcn_s_setprio(0);                                                   \
    __builtin_amdgcn_s_barrier();                                                    \
    __builtin_amdgcn_sched_barrier(0);                                               \
  }

  for (int t = 0; t < NT; t += 2) {
    GEMM_TILE(t,     Bc, Bn)
    GEMM_TILE(t + 1, Bn, Bc)
  }
#undef GEMM_TILE

  const int row0 = bm * 256 + wr * 128;
  const int col0 = bn * 256 + wcn * 64;

  if constexpr (EPI == 1) {
    float* Cb = (float*)O0 + (long)bz * sC;
    const float g = gptr[0];
#pragma unroll
    for (int i = 0; i < 8; ++i)
#pragma unroll
      for (int j = 0; j < 4; ++j) {
        const int col = col0 + j * 16 + l15;
        const float tl = tailor[bz * 1024 + col];
#pragma unroll
        for (int r = 0; r < 4; ++r) {
          const int row = row0 + i * 16 + lk * 4 + r;
          const long idx = ((long)bz * 2048 + row) * 1024 + col;
          Cb[(long)row * 1024 + col] = b2f(xh[idx]) + g * ((Vsum[bz * 2048 + row] + acc[i][j][r]) * tl);
        }
      }
  } else if constexpr (EPI == 4) {
    unsigned short* Cb = (unsigned short*)O0 + (long)bz * sC;
#pragma unroll
    for (int i = 0; i < 8; ++i) {
#pragma unroll
      for (int j = 0; j < 4; ++j) {
        const int col = col0 + j * 16 + l15;
#pragma unroll
        for (int r = 0; r < 4; ++r) {
          const int row = row0 + i * 16 + lk * 4 + r;
          Cb[(long)row * 1024 + col] = f2b(acc[i][j][r]);
        }
      }
#pragma unroll
      for (int r = 0; r < 4; ++r) {
        float sm = acc[i][0][r] + acc[i][1][r] + acc[i][2][r] + acc[i][3][r];
        sm = red16(sm);
        if (l15 == 0) {
          const int row = row0 + i * 16 + lk * 4 + r;
          atomicAdd(&r4[(long)bz * 1024 + row], sm);
        }
      }
    }
  } else {  // EPI == 5: merged QKV
    const int seg = bn >> 2;             // 0=Q, 1=K, 2=V
    unsigned short* outp = seg == 0 ? (unsigned short*)O0
                        : seg == 1 ? (unsigned short*)O1 : (unsigned short*)O2;
    const int b = bm >> 3;               // batch (2048 rows per batch, 8 m-tiles)
    float bvj[4];
#pragma unroll
    for (int j = 0; j < 4; ++j) bvj[j] = bias[col0 + j * 16 + l15];
    const int colL0 = col0 & 1023;
#pragma unroll
    for (int i = 0; i < 8; ++i)
#pragma unroll
      for (int j = 0; j < 4; ++j) {
        const int colL = colL0 + j * 16 + l15;
#pragma unroll
        for (int r = 0; r < 4; ++r) {
          const int row = row0 + i * 16 + lk * 4 + r;
          outp[(long)row * 1024 + colL] = f2b(acc[i][j][r] + bvj[j]);
        }
      }
    if (seg < 2) {
      // per-column sumsq (and sum for Q) over this block's 256 rows
#pragma unroll
      for (int j = 0; j < 4; ++j) {
        const int colL = colL0 + j * 16 + l15;
        float ss = 0.f, sm = 0.f;
#pragma unroll
        for (int i = 0; i < 8; ++i)
#pragma unroll
          for (int r = 0; r < 4; ++r) {
            const float v = acc[i][j][r] + bvj[j];
            ss += v * v; sm += v;
          }
        ss = red4lk(ss);
        if (seg == 0) sm = red4lk(sm);
        if (lk == 0) {
          atomicAdd(&(seg == 0 ? r1 : r3)[(long)b * 1024 + colL], ss);
          if (seg == 0) atomicAdd(&r2[(long)b * 1024 + colL], sm);
        }
      }
    } else {
      // per-row sum over this block's 256 cols (V row-sums)
#pragma unroll
      for (int i = 0; i < 8; ++i)
#pragma unroll
        for (int r = 0; r < 4; ++r) {
          float sm = 0.f;
#pragma unroll
          for (int j = 0; j < 4; ++j) sm += acc[i][j][r] + bvj[j];
          sm = red16(sm);
          if (l15 == 0) {
            const int row = row0 + i * 16 + lk * 4 + r;
            atomicAdd(&r4[row], sm);
          }
        }
    }
  }
}

extern "C" void kernel_launch(void* const* d_in, const int* in_sizes, int n_in,
                              void* d_out, int out_size, void* d_ws, size_t ws_size,
                              hipStream_t stream) {
  (void)in_sizes; (void)n_in; (void)out_size;
  const float* x     = (const float*)d_in[0];
  const float* Wq    = (const float*)d_in[1];
  const float* bq    = (const float*)d_in[2];
  const float* Wk    = (const float*)d_in[3];
  const float* bk    = (const float*)d_in[4];
  const float* Wv    = (const float*)d_in[5];
  const float* bv    = (const float*)d_in[6];
  const float* gamma = (const float*)d_in[7];

  // B=16, C=2048, L=D=1024
  const long NE = 16L * 2048 * 1024;
  const long BUF = NE * 2;                    // bytes per bf16 tensor

  char* w = (char*)d_ws;
  unsigned short* Qh  = (unsigned short*)(w);            // later overlaid by S
  unsigned short* Kh  = (unsigned short*)(w + BUF);      // later overlaid by QT
  unsigned short* Vh  = (unsigned short*)(w + 2 * BUF);
  unsigned short* xh  = (unsigned short*)(w + 3 * BUF);  // live to the end
  unsigned short* KnT = (unsigned short*)(w + 4 * BUF);
  unsigned short* S   = Qh;
  unsigned short* QT  = Kh;
  size_t off = 5 * (size_t)BUF;
  unsigned short* Wqkvh = (unsigned short*)(w + off); off += 3 * 2097152;  // Wq|Wk|Wv contiguous
  char* accbase = w + off;
  float* pq     = (float*)(w + off); off += 65536;       // col sumsq of Q  (16x1024)
  float* qsum   = (float*)(w + off); off += 65536;       // col sum of Q
  float* pk     = (float*)(w + off); off += 65536;       // col sumsq of K
  float* Vsum   = (float*)(w + off); off += 131072;      // row sum of V    (16x2048)
  float* Srow   = (float*)(w + off); off += 65536;       // row sum of S    (16x1024)
  const size_t accbytes = (size_t)(w + off - accbase);
  float* invq   = (float*)(w + off); off += 65536;
  float* invk   = (float*)(w + off); off += 65536;
  float* tailor = (float*)(w + off); off += 65536;
  float* bqkv   = (float*)(w + off); off += 12288;
  if (ws_size < off) return;

  // 0) zero atomic accumulators
  hipMemsetAsync(accbase, 0, accbytes, stream);

  // 1) casts + bias concat
  k_f32_to_bf16<<<dim3((unsigned)(NE / 1024)), 256, 0, stream>>>(x, xh, NE);
  k_f32_to_bf16<<<dim3(1024), 256, 0, stream>>>(Wq, Wqkvh, 1048576);
  k_f32_to_bf16<<<dim3(1024), 256, 0, stream>>>(Wk, Wqkvh + 1048576, 1048576);
  k_f32_to_bf16<<<dim3(1024), 256, 0, stream>>>(Wv, Wqkvh + 2097152, 1048576);
  k_bias_cat<<<dim3(12), 256, 0, stream>>>(bq, bk, bv, bqkv);

  // 2) merged QKV GEMM: M=32768, N=3072, K=1024 + fused reductions
  k_g256<5><<<dim3(12, 128, 1), 512, 0, stream>>>(
      xh, Wqkvh, Qh, Kh, Vh, 1024, 0, 0, 0, bqkv,
      pq, qsum, pk, Vsum, nullptr, nullptr, nullptr, nullptr);

  // 3) inverse norms
  k_norms_fin<<<dim3(64), 256, 0, stream>>>(pq, pk, invq, invk);

  // 4) KnT = T(Kh)*invk   (before QT overlays Kh)
  k_transpose_scale<<<dim3(32, 16, 16), 256, 0, stream>>>(Kh, invk, KnT);

  // 5) QT = T(Qh)*invq    (overlays Kh)
  k_transpose_scale<<<dim3(32, 16, 16), 256, 0, stream>>>(Qh, invq, QT);

  // 6) S = QT x KnT^T per batch (M=N=1024, K=2048) + row sums — overlays Qh
  k_g256<4><<<dim3(4, 4, 16), 512, 0, stream>>>(
      QT, KnT, S, nullptr, nullptr, 2048, 1024L * 2048, 1024L * 2048, 1024L * 1024,
      nullptr, nullptr, nullptr, nullptr, Srow, nullptr, nullptr, nullptr, nullptr);

  // 7) tailor
  k_tailor_fin<<<dim3(64), 256, 0, stream>>>(Srow, invq, qsum, tailor);

  // 8) out = xh + gamma*(Vsum + V x S^T) * tailor   (M=2048/batch, N=1024, K=1024)
  k_g256<1><<<dim3(4, 8, 16), 512, 0, stream>>>(
      Vh, S, d_out, nullptr, nullptr, 1024, 2048L * 1024, 1024L * 1024, 2048L * 1024,
      nullptr, nullptr, nullptr, nullptr, nullptr, xh, Vsum, tailor, gamma);
}

// Round 9
// 539.633 us; speedup vs baseline: 1.1839x; 1.0367x over previous
//
#include <hip/hip_runtime.h>
#include <cstdint>

#define DEV static __device__ __forceinline__

typedef __attribute__((ext_vector_type(8))) short short8v;     // 8 x bf16 bits
typedef __attribute__((ext_vector_type(4))) float f32x4;
typedef __attribute__((ext_vector_type(4))) float fl4;
typedef __attribute__((ext_vector_type(4))) unsigned short us4;
typedef __attribute__((ext_vector_type(8))) unsigned short us8;

DEV float b2f(unsigned short u) {
  union { unsigned int i; float f; } c; c.i = ((unsigned int)u) << 16; return c.f;
}
DEV unsigned short f2b(float f) {   // RNE float -> bf16 bits
  union { float f; unsigned int i; } c; c.f = f;
  unsigned int u = c.i;
  u += 0x7fffu + ((u >> 16) & 1u);
  return (unsigned short)(u >> 16);
}

DEV void gload16(const void* g, void* l) {  // async global->LDS, 16B/lane
  __builtin_amdgcn_global_load_lds(
      (const __attribute__((address_space(1))) unsigned int*)g,
      (__attribute__((address_space(3))) unsigned int*)l, 16, 0, 0);
}

DEV float red16(float v) {  // reduce across 16 lanes sharing lk (xor low 4 bits)
  v += __shfl_xor(v, 1); v += __shfl_xor(v, 2);
  v += __shfl_xor(v, 4); v += __shfl_xor(v, 8);
  return v;
}
DEV float red4lk(float v) { // reduce across the 4 lk groups (xor bits 4,5)
  v += __shfl_xor(v, 16); v += __shfl_xor(v, 32);
  return v;
}

// ---------------- elementwise f32 -> bf16 ----------------
__global__ __launch_bounds__(256) void k_f32_to_bf16(const float* __restrict__ src,
                                                     unsigned short* __restrict__ dst, long n) {
  long i = ((long)blockIdx.x * 256 + threadIdx.x) * 4;
  if (i >= n) return;
  fl4 v = *(const fl4*)(src + i);
  us4 o;
  o[0] = f2b(v[0]); o[1] = f2b(v[1]); o[2] = f2b(v[2]); o[3] = f2b(v[3]);
  *(us4*)(dst + i) = o;
}

// ---------------- concat biases into 3072-float buffer ----------------
__global__ __launch_bounds__(256) void k_bias_cat(const float* __restrict__ bq,
                                                  const float* __restrict__ bk,
                                                  const float* __restrict__ bv,
                                                  float* __restrict__ o) {
  const int t = blockIdx.x * 256 + threadIdx.x;   // 3072
  o[t] = t < 1024 ? bq[t] : (t < 2048 ? bk[t - 1024] : bv[t - 2048]);
}

// ---------------- finalize inverse norms ----------------
__global__ __launch_bounds__(256) void k_norms_fin(const float* __restrict__ pq,
                                                   const float* __restrict__ pk,
                                                   float* __restrict__ invq, float* __restrict__ invk) {
  const int gid = blockIdx.x * 256 + threadIdx.x;   // 16384
  invq[gid] = rsqrtf(pq[gid]);
  invk[gid] = rsqrtf(pk[gid]);
}

// ---------------- finalize tailor: 1/(L + rowsum(S) + eps*invq*colsum(Q)) ----------------
__global__ __launch_bounds__(256) void k_tailor_fin(const float* __restrict__ Srow,
                                                    const float* __restrict__ invq,
                                                    const float* __restrict__ qsum,
                                                    float* __restrict__ tailor) {
  const int gid = blockIdx.x * 256 + threadIdx.x;   // 16384
  tailor[gid] = 1.0f / (1024.0f + Srow[gid] + 1e-6f * invq[gid] * qsum[gid]);
}

// ---------------- transpose+scale: (B,2048,1024) -> (B,1024,2048), dst row j scaled ----------------
__global__ __launch_bounds__(256) void k_transpose_scale(const unsigned short* __restrict__ Q,
                                                         const float* __restrict__ scale,
                                                         unsigned short* __restrict__ QT) {
  __shared__ unsigned short tile[64][68];
  const int c0 = blockIdx.x * 64, n0 = blockIdx.y * 64, b = blockIdx.z;
  const int jr = (threadIdx.x & 15) * 4;
  const int ir = threadIdx.x >> 4;
  const unsigned short* src = Q + ((long)b * 2048 + c0) * 1024 + n0;
#pragma unroll
  for (int p = 0; p < 4; ++p) {
    int i = ir + p * 16;
    *(us4*)&tile[i][jr] = *(const us4*)(src + (long)i * 1024 + jr);
  }
  __syncthreads();
  unsigned short* dst = QT + ((long)b * 1024 + n0) * 2048 + c0;
#pragma unroll
  for (int p = 0; p < 4; ++p) {
    int j = ir + p * 16;
    const float s = scale[b * 1024 + n0 + j];
    us4 o;
    o[0] = f2b(b2f(tile[jr + 0][j]) * s);
    o[1] = f2b(b2f(tile[jr + 1][j]) * s);
    o[2] = f2b(b2f(tile[jr + 2][j]) * s);
    o[3] = f2b(b2f(tile[jr + 3][j]) * s);
    *(us4*)(dst + (long)j * 2048 + jr) = o;
  }
}

#define MFMA_BF16 __builtin_amdgcn_mfma_f32_16x16x32_bf16
#define SCHED0 __builtin_amdgcn_sched_barrier(0)
#define SBAR   __builtin_amdgcn_s_barrier()
#define LGKM0  asm volatile("s_waitcnt lgkmcnt(0)" ::: "memory")

// ---------------- 256x256 NT GEMM, BK=64, 8 waves (2Mx4N), m201-style 4-phase/K-tile ----
// Per K-tile t (4 phases x 16 MFMA, each one C-quadrant x K=64):
//   ph0: read {B nh0 (4), A mh0 (8)} | stage B q0,q1(t+1) | SCHED0 SBAR LGKM0 SCHED0 | MFMA | SBAR
//   ph1: read {B nh1 (4)}            | stage B q2,q3       | ... MFMA | vmcnt(4|0) SBAR
//   ph2: read {A mh1 (8)}            | stage A q0,q2       | ... MFMA | SBAR
//   ph3: (no reads)                  | stage A q1,q3       | SBAR MFMA | vmcnt(2) SBAR
// Stage order chosen so every vmcnt is counted (4,2 — never 0 until tail): the 2 loads
// allowed outstanding at tile top are exactly A q1,q3 (not read until ph2, drained by the
// ph1-end vmcnt(4)). Reads issue PRE-barrier, drain with lgkmcnt(0)+sched_barrier(0)
// POST-barrier (rule #18). 2 LDS dbufs = 128 KiB. LDS chunk-swizzle (verified 0-conflict):
// logical (row, chunk c in [0,8)) stored at physical chunk c^(row&7); stage pre-swizzles
// the GLOBAL source chunk; reads apply the same XOR (l15-only).
// C[m][n] = sum_k A[m][k] * Bt[n][k]; out col-stride fixed 1024.
// EPI 1: final fused fp32 epilogue.  EPI 4: bf16 out + per-row atomic sum.  EPI 5: merged QKV.
template<int EPI>
__global__ __launch_bounds__(512)
void k_g256(const unsigned short* __restrict__ A,
            const unsigned short* __restrict__ Bt,
            void* __restrict__ O0, void* __restrict__ O1, void* __restrict__ O2,
            int K, long sA, long sB, long sC,
            const float* __restrict__ bias,
            float* __restrict__ r1, float* __restrict__ r2,
            float* __restrict__ r3, float* __restrict__ r4,
            const unsigned short* __restrict__ xh,
            const float* __restrict__ Vsum,
            const float* __restrict__ tailor,
            const float* __restrict__ gptr) {
  __shared__ __align__(16) unsigned short As[2][16384];   // 2 x 256x64 bf16 = 64 KiB
  __shared__ __align__(16) unsigned short Bs[2][16384];   // 64 KiB  (total 128 KiB)

  const int tid = threadIdx.x;
  const int wv = tid >> 6, lane = tid & 63;
  const int wr = wv >> 2, wcn = wv & 3;          // 2 x 4 wave grid
  const int l15 = lane & 15, lk = lane >> 4;

  // XCD-bijective swizzle over (x,y); nwg % 8 == 0 for all grids used
  const int nx = gridDim.x;
  const int nwg = nx * gridDim.y;
  const int lin = blockIdx.y * nx + blockIdx.x;
  const int cpx = nwg >> 3;
  const int wg = (lin & 7) * cpx + (lin >> 3);
  const int bn = wg % nx;
  const int bm = wg / nx;
  const int bz = blockIdx.z;

  const unsigned short* Ab = A + (long)bz * sA + (long)bm * 256 * K;
  const unsigned short* Bb = Bt + (long)bz * sB + (long)bn * 256 * K;

  // staging: quarter Q covers rows [64Q,64Q+64) x 64 k (8 KiB = 1 block-wide gload16).
  // thread tid: row 64Q + (tid>>3), physical chunk tid&7, pre-swizzled global chunk
  // cg = (tid&7) ^ (row&7)  (64Q doesn't affect &7). LDS dst: Q*4096 + wv*512 (elements).
  const int srow = tid >> 3;
  const int cg = (tid & 7) ^ (srow & 7);
  const long gOff = (long)srow * K + (long)cg * 8;   // + 64Q*K + t*64
  const int ldsb = wv * 512;

  // read side: frag (row r, kstep ks in {0,1}): elem = r*64 + ((ks*4+lk)^(r&7))*8; r&7==l15&7.
  const int sw0 = ((lk) ^ (l15 & 7)) * 8;
  const int sw1 = ((4 + lk) ^ (l15 & 7)) * 8;
  const int abase = (wr * 128 + l15) * 64;   // + i*1024 per 16-row step
  const int bbase = (wcn * 64 + l15) * 64;   // + j*1024

  f32x4 acc[8][4];
#pragma unroll
  for (int i = 0; i < 8; ++i)
#pragma unroll
    for (int j = 0; j < 4; ++j) acc[i][j] = (f32x4){0.f, 0.f, 0.f, 0.f};

  // prologue: tile 0 -> buf 0, in consumption-safe order B0,B1,B2,B3,A0,A2,A1,A3
  gload16(Bb + 0L * 64 * K + gOff, &Bs[0][0 * 4096 + ldsb]);
  gload16(Bb + 1L * 64 * K + gOff, &Bs[0][1 * 4096 + ldsb]);
  gload16(Bb + 2L * 64 * K + gOff, &Bs[0][2 * 4096 + ldsb]);
  gload16(Bb + 3L * 64 * K + gOff, &Bs[0][3 * 4096 + ldsb]);
  gload16(Ab + 0L * 64 * K + gOff, &As[0][0 * 4096 + ldsb]);
  gload16(Ab + 2L * 64 * K + gOff, &As[0][2 * 4096 + ldsb]);
  gload16(Ab + 1L * 64 * K + gOff, &As[0][1 * 4096 + ldsb]);
  gload16(Ab + 3L * 64 * K + gOff, &As[0][3 * 4096 + ldsb]);
  asm volatile("s_waitcnt vmcnt(2)" ::: "memory");   // A q1,q3 may lag (needed at ph2)
  SBAR;

  short8v Af[4][2], Bf[4][2];
  const int NT = K >> 6;

  for (int t = 0; t < NT; ++t) {
    const int cb = t & 1;
    const unsigned short* Asc = &As[cb][0];
    const unsigned short* Bsc = &Bs[cb][0];
    unsigned short* Asn = &As[cb ^ 1][0];
    unsigned short* Bsn = &Bs[cb ^ 1][0];
    const bool more = (t + 1 < NT);
    const long kb = (long)(t + 1) * 64;

    // ---------- ph0: read B nh0 + A mh0; stage B q0,q1
#pragma unroll
    for (int j = 0; j < 2; ++j) {
      Bf[j][0] = *(const short8v*)&Bsc[bbase + j * 1024 + sw0];
      Bf[j][1] = *(const short8v*)&Bsc[bbase + j * 1024 + sw1];
    }
#pragma unroll
    for (int i = 0; i < 4; ++i) {
      Af[i][0] = *(const short8v*)&Asc[abase + i * 1024 + sw0];
      Af[i][1] = *(const short8v*)&Asc[abase + i * 1024 + sw1];
    }
    if (more) {
      gload16(Bb + kb + gOff,             &Bsn[ldsb]);
      gload16(Bb + kb + gOff + 64L * K,   &Bsn[4096 + ldsb]);
    }
    SCHED0; SBAR; LGKM0; SCHED0;
    __builtin_amdgcn_s_setprio(1);
#pragma unroll
    for (int i = 0; i < 4; ++i)
#pragma unroll
      for (int j = 0; j < 2; ++j) {
        acc[i][j] = MFMA_BF16(Af[i][0], Bf[j][0], acc[i][j], 0, 0, 0);
        acc[i][j] = MFMA_BF16(Af[i][1], Bf[j][1], acc[i][j], 0, 0, 0);
      }
    __builtin_amdgcn_s_setprio(0);
    SCHED0; SBAR;

    // ---------- ph1: read B nh1; stage B q2,q3; counted vmcnt at end
#pragma unroll
    for (int j = 2; j < 4; ++j) {
      Bf[j][0] = *(const short8v*)&Bsc[bbase + j * 1024 + sw0];
      Bf[j][1] = *(const short8v*)&Bsc[bbase + j * 1024 + sw1];
    }
    if (more) {
      gload16(Bb + kb + gOff + 128L * K,  &Bsn[8192 + ldsb]);
      gload16(Bb + kb + gOff + 192L * K,  &Bsn[12288 + ldsb]);
    }
    SCHED0; SBAR; LGKM0; SCHED0;
    __builtin_amdgcn_s_setprio(1);
#pragma unroll
    for (int i = 0; i < 4; ++i)
#pragma unroll
      for (int j = 2; j < 4; ++j) {
        acc[i][j] = MFMA_BF16(Af[i][0], Bf[j][0], acc[i][j], 0, 0, 0);
        acc[i][j] = MFMA_BF16(Af[i][1], Bf[j][1], acc[i][j], 0, 0, 0);
      }
    __builtin_amdgcn_s_setprio(0);
    SCHED0;
    if (more) { asm volatile("s_waitcnt vmcnt(4)" ::: "memory"); }   // drains A q1,q3 of tile t
    else      { asm volatile("s_waitcnt vmcnt(0)" ::: "memory"); }
    SBAR;

    // ---------- ph2: read A mh1; stage A q0,q2
#pragma unroll
    for (int i = 0; i < 4; ++i) {
      Af[i][0] = *(const short8v*)&Asc[abase + (i + 4) * 1024 + sw0];
      Af[i][1] = *(const short8v*)&Asc[abase + (i + 4) * 1024 + sw1];
    }
    if (more) {
      gload16(Ab + kb + gOff,             &Asn[ldsb]);
      gload16(Ab + kb + gOff + 128L * K,  &Asn[8192 + ldsb]);
    }
    SCHED0; SBAR; LGKM0; SCHED0;
    __builtin_amdgcn_s_setprio(1);
#pragma unroll
    for (int i = 0; i < 4; ++i)
#pragma unroll
      for (int j = 0; j < 2; ++j) {
        acc[i + 4][j] = MFMA_BF16(Af[i][0], Bf[j][0], acc[i + 4][j], 0, 0, 0);
        acc[i + 4][j] = MFMA_BF16(Af[i][1], Bf[j][1], acc[i + 4][j], 0, 0, 0);
      }
    __builtin_amdgcn_s_setprio(0);
    SCHED0; SBAR;

    // ---------- ph3: no reads; stage A q1,q3; MFMA mh1 x nh1; counted vmcnt at end
    if (more) {
      gload16(Ab + kb + gOff + 64L * K,   &Asn[4096 + ldsb]);
      gload16(Ab + kb + gOff + 192L * K,  &Asn[12288 + ldsb]);
    }
    SCHED0; SBAR;
    __builtin_amdgcn_s_setprio(1);
#pragma unroll
    for (int i = 0; i < 4; ++i)
#pragma unroll
      for (int j = 2; j < 4; ++j) {
        acc[i + 4][j] = MFMA_BF16(Af[i][0], Bf[j][0], acc[i + 4][j], 0, 0, 0);
        acc[i + 4][j] = MFMA_BF16(Af[i][1], Bf[j][1], acc[i + 4][j], 0, 0, 0);
      }
    __builtin_amdgcn_s_setprio(0);
    SCHED0;
    if (more) { asm volatile("s_waitcnt vmcnt(2)" ::: "memory"); }   // allow A q1,q3 of t+1
    SBAR;
  }

  const int row0 = bm * 256 + wr * 128;
  const int col0 = bn * 256 + wcn * 64;

  if constexpr (EPI == 1) {
    float* Cb = (float*)O0 + (long)bz * sC;
    const float g = gptr[0];
#pragma unroll
    for (int i = 0; i < 8; ++i)
#pragma unroll
      for (int j = 0; j < 4; ++j) {
        const int col = col0 + j * 16 + l15;
        const float tl = tailor[bz * 1024 + col];
#pragma unroll
        for (int r = 0; r < 4; ++r) {
          const int row = row0 + i * 16 + lk * 4 + r;
          const long idx = ((long)bz * 2048 + row) * 1024 + col;
          Cb[(long)row * 1024 + col] = b2f(xh[idx]) + g * ((Vsum[bz * 2048 + row] + acc[i][j][r]) * tl);
        }
      }
  } else if constexpr (EPI == 4) {
    unsigned short* Cb = (unsigned short*)O0 + (long)bz * sC;
#pragma unroll
    for (int i = 0; i < 8; ++i) {
#pragma unroll
      for (int j = 0; j < 4; ++j) {
        const int col = col0 + j * 16 + l15;
#pragma unroll
        for (int r = 0; r < 4; ++r) {
          const int row = row0 + i * 16 + lk * 4 + r;
          Cb[(long)row * 1024 + col] = f2b(acc[i][j][r]);
        }
      }
#pragma unroll
      for (int r = 0; r < 4; ++r) {
        float sm = acc[i][0][r] + acc[i][1][r] + acc[i][2][r] + acc[i][3][r];
        sm = red16(sm);
        if (l15 == 0) {
          const int row = row0 + i * 16 + lk * 4 + r;
          atomicAdd(&r4[(long)bz * 1024 + row], sm);
        }
      }
    }
  } else {  // EPI == 5: merged QKV
    const int seg = bn >> 2;             // 0=Q, 1=K, 2=V
    unsigned short* outp = seg == 0 ? (unsigned short*)O0
                        : seg == 1 ? (unsigned short*)O1 : (unsigned short*)O2;
    const int b = bm >> 3;               // batch (2048 rows per batch, 8 m-tiles)
    float bvj[4];
#pragma unroll
    for (int j = 0; j < 4; ++j) bvj[j] = bias[col0 + j * 16 + l15];
    const int colL0 = col0 & 1023;
#pragma unroll
    for (int i = 0; i < 8; ++i)
#pragma unroll
      for (int j = 0; j < 4; ++j) {
        const int colL = colL0 + j * 16 + l15;
#pragma unroll
        for (int r = 0; r < 4; ++r) {
          const int row = row0 + i * 16 + lk * 4 + r;
          outp[(long)row * 1024 + colL] = f2b(acc[i][j][r] + bvj[j]);
        }
      }
    if (seg < 2) {
      // per-column sumsq (and sum for Q) over this block's 256 rows
#pragma unroll
      for (int j = 0; j < 4; ++j) {
        const int colL = colL0 + j * 16 + l15;
        float ss = 0.f, sm = 0.f;
#pragma unroll
        for (int i = 0; i < 8; ++i)
#pragma unroll
          for (int r = 0; r < 4; ++r) {
            const float v = acc[i][j][r] + bvj[j];
            ss += v * v; sm += v;
          }
        ss = red4lk(ss);
        if (seg == 0) sm = red4lk(sm);
        if (lk == 0) {
          atomicAdd(&(seg == 0 ? r1 : r3)[(long)b * 1024 + colL], ss);
          if (seg == 0) atomicAdd(&r2[(long)b * 1024 + colL], sm);
        }
      }
    } else {
      // per-row sum over this block's 256 cols (V row-sums)
#pragma unroll
      for (int i = 0; i < 8; ++i)
#pragma unroll
        for (int r = 0; r < 4; ++r) {
          float sm = 0.f;
#pragma unroll
          for (int j = 0; j < 4; ++j) sm += acc[i][j][r] + bvj[j];
          sm = red16(sm);
          if (l15 == 0) {
            const int row = row0 + i * 16 + lk * 4 + r;
            atomicAdd(&r4[row], sm);
          }
        }
    }
  }
}

extern "C" void kernel_launch(void* const* d_in, const int* in_sizes, int n_in,
                              void* d_out, int out_size, void* d_ws, size_t ws_size,
                              hipStream_t stream) {
  (void)in_sizes; (void)n_in; (void)out_size;
  const float* x     = (const float*)d_in[0];
  const float* Wq    = (const float*)d_in[1];
  const float* bq    = (const float*)d_in[2];
  const float* Wk    = (const float*)d_in[3];
  const float* bk    = (const float*)d_in[4];
  const float* Wv    = (const float*)d_in[5];
  const float* bv    = (const float*)d_in[6];
  const float* gamma = (const float*)d_in[7];

  // B=16, C=2048, L=D=1024
  const long NE = 16L * 2048 * 1024;
  const long BUF = NE * 2;                    // bytes per bf16 tensor

  char* w = (char*)d_ws;
  unsigned short* Qh  = (unsigned short*)(w);            // later overlaid by S
  unsigned short* Kh  = (unsigned short*)(w + BUF);      // later overlaid by QT
  unsigned short* Vh  = (unsigned short*)(w + 2 * BUF);
  unsigned short* xh  = (unsigned short*)(w + 3 * BUF);  // live to the end
  unsigned short* KnT = (unsigned short*)(w + 4 * BUF);
  unsigned short* S   = Qh;
  unsigned short* QT  = Kh;
  size_t off = 5 * (size_t)BUF;
  unsigned short* Wqkvh = (unsigned short*)(w + off); off += 3 * 2097152;  // Wq|Wk|Wv contiguous
  char* accbase = w + off;
  float* pq     = (float*)(w + off); off += 65536;       // col sumsq of Q  (16x1024)
  float* qsum   = (float*)(w + off); off += 65536;       // col sum of Q
  float* pk     = (float*)(w + off); off += 65536;       // col sumsq of K
  float* Vsum   = (float*)(w + off); off += 131072;      // row sum of V    (16x2048)
  float* Srow   = (float*)(w + off); off += 65536;       // row sum of S    (16x1024)
  const size_t accbytes = (size_t)(w + off - accbase);
  float* invq   = (float*)(w + off); off += 65536;
  float* invk   = (float*)(w + off); off += 65536;
  float* tailor = (float*)(w + off); off += 65536;
  float* bqkv   = (float*)(w + off); off += 12288;
  if (ws_size < off) return;

  // 0) zero atomic accumulators
  hipMemsetAsync(accbase, 0, accbytes, stream);

  // 1) casts + bias concat
  k_f32_to_bf16<<<dim3((unsigned)(NE / 1024)), 256, 0, stream>>>(x, xh, NE);
  k_f32_to_bf16<<<dim3(1024), 256, 0, stream>>>(Wq, Wqkvh, 1048576);
  k_f32_to_bf16<<<dim3(1024), 256, 0, stream>>>(Wk, Wqkvh + 1048576, 1048576);
  k_f32_to_bf16<<<dim3(1024), 256, 0, stream>>>(Wv, Wqkvh + 2097152, 1048576);
  k_bias_cat<<<dim3(12), 256, 0, stream>>>(bq, bk, bv, bqkv);

  // 2) merged QKV GEMM: M=32768, N=3072, K=1024 + fused reductions
  k_g256<5><<<dim3(12, 128, 1), 512, 0, stream>>>(
      xh, Wqkvh, Qh, Kh, Vh, 1024, 0, 0, 0, bqkv,
      pq, qsum, pk, Vsum, nullptr, nullptr, nullptr, nullptr);

  // 3) inverse norms
  k_norms_fin<<<dim3(64), 256, 0, stream>>>(pq, pk, invq, invk);

  // 4) KnT = T(Kh)*invk   (before QT overlays Kh)
  k_transpose_scale<<<dim3(32, 16, 16), 256, 0, stream>>>(Kh, invk, KnT);

  // 5) QT = T(Qh)*invq    (overlays Kh)
  k_transpose_scale<<<dim3(32, 16, 16), 256, 0, stream>>>(Qh, invq, QT);

  // 6) S = QT x KnT^T per batch (M=N=1024, K=2048) + row sums — overlays Qh
  k_g256<4><<<dim3(4, 4, 16), 512, 0, stream>>>(
      QT, KnT, S, nullptr, nullptr, 2048, 1024L * 2048, 1024L * 2048, 1024L * 1024,
      nullptr, nullptr, nullptr, nullptr, Srow, nullptr, nullptr, nullptr, nullptr);

  // 7) tailor
  k_tailor_fin<<<dim3(64), 256, 0, stream>>>(Srow, invq, qsum, tailor);

  // 8) out = xh + gamma*(Vsum + V x S^T) * tailor   (M=2048/batch, N=1024, K=1024)
  k_g256<1><<<dim3(4, 8, 16), 512, 0, stream>>>(
      Vh, S, d_out, nullptr, nullptr, 1024, 2048L * 1024, 1024L * 1024, 2048L * 1024,
      nullptr, nullptr, nullptr, nullptr, nullptr, xh, Vsum, tailor, gamma);
}

// Round 10
// 499.214 us; speedup vs baseline: 1.2797x; 1.0810x over previous
//
#include <hip/hip_runtime.h>
#include <cstdint>

#define DEV static __device__ __forceinline__

typedef __attribute__((ext_vector_type(8))) short short8v;     // 8 x bf16 bits
typedef __attribute__((ext_vector_type(4))) float f32x4;
typedef __attribute__((ext_vector_type(4))) float fl4;
typedef __attribute__((ext_vector_type(4))) unsigned short us4;
typedef __attribute__((ext_vector_type(8))) unsigned short us8;

DEV float b2f(unsigned short u) {
  union { unsigned int i; float f; } c; c.i = ((unsigned int)u) << 16; return c.f;
}
DEV unsigned short f2b(float f) {   // RNE float -> bf16 bits
  union { float f; unsigned int i; } c; c.f = f;
  unsigned int u = c.i;
  u += 0x7fffu + ((u >> 16) & 1u);
  return (unsigned short)(u >> 16);
}

DEV void gload16(const void* g, void* l) {  // async global->LDS, 16B/lane
  __builtin_amdgcn_global_load_lds(
      (const __attribute__((address_space(1))) unsigned int*)g,
      (__attribute__((address_space(3))) unsigned int*)l, 16, 0, 0);
}

DEV float red16(float v) {  // reduce across 16 lanes sharing lk (xor low 4 bits)
  v += __shfl_xor(v, 1); v += __shfl_xor(v, 2);
  v += __shfl_xor(v, 4); v += __shfl_xor(v, 8);
  return v;
}
DEV float red4lk(float v) { // reduce across the 4 lk groups (xor bits 4,5)
  v += __shfl_xor(v, 16); v += __shfl_xor(v, 32);
  return v;
}

// ---------------- elementwise f32 -> bf16 ----------------
__global__ __launch_bounds__(256) void k_f32_to_bf16(const float* __restrict__ src,
                                                     unsigned short* __restrict__ dst, long n) {
  long i = ((long)blockIdx.x * 256 + threadIdx.x) * 4;
  if (i >= n) return;
  fl4 v = *(const fl4*)(src + i);
  us4 o;
  o[0] = f2b(v[0]); o[1] = f2b(v[1]); o[2] = f2b(v[2]); o[3] = f2b(v[3]);
  *(us4*)(dst + i) = o;
}

// ---------------- concat biases into 3072-float buffer ----------------
__global__ __launch_bounds__(256) void k_bias_cat(const float* __restrict__ bq,
                                                  const float* __restrict__ bk,
                                                  const float* __restrict__ bv,
                                                  float* __restrict__ o) {
  const int t = blockIdx.x * 256 + threadIdx.x;   // 3072
  o[t] = t < 1024 ? bq[t] : (t < 2048 ? bk[t - 1024] : bv[t - 2048]);
}

// ---------------- finalize inverse norms ----------------
__global__ __launch_bounds__(256) void k_norms_fin(const float* __restrict__ pq,
                                                   const float* __restrict__ pk,
                                                   float* __restrict__ invq, float* __restrict__ invk) {
  const int gid = blockIdx.x * 256 + threadIdx.x;   // 16384
  invq[gid] = rsqrtf(pq[gid]);
  invk[gid] = rsqrtf(pk[gid]);
}

// ---------------- finalize tailor: 1/(L + rowsum(S) + eps*invq*colsum(Q)) ----------------
__global__ __launch_bounds__(256) void k_tailor_fin(const float* __restrict__ Srow,
                                                    const float* __restrict__ invq,
                                                    const float* __restrict__ qsum,
                                                    float* __restrict__ tailor) {
  const int gid = blockIdx.x * 256 + threadIdx.x;   // 16384
  tailor[gid] = 1.0f / (1024.0f + Srow[gid] + 1e-6f * invq[gid] * qsum[gid]);
}

#define MFMA_BF16 __builtin_amdgcn_mfma_f32_16x16x32_bf16
#define SCHED0 __builtin_amdgcn_sched_barrier(0)
#define SBAR   __builtin_amdgcn_s_barrier()
#define LGKM0  asm volatile("s_waitcnt lgkmcnt(0)" ::: "memory")

// ---------------- 256x256 NT GEMM, BK=64, 8 waves (2Mx4N), m201-style 4-phase/K-tile ----
// K-loop identical to R9 (verified). Epilogues:
// EPI 1: final fused fp32 epilogue (residual bf16 xh, Vsum, tailor, gamma).
// EPI 4: S-GEMM: scaled bf16 out S[p][l] = invq[p]*invk[l]*acc + per-row atomic sum of
//        the SCALED values into Srow.  (r1=Srow, r2=invq, r3=invk)
// EPI 5: merged QKV: seg0/1 (Q/K) store TRANSPOSED (QT/KT: [b][1024 p][2048 m], us4 per
//        (i,j) — lane's 4 acc values are consecutive in m = contiguous dim) + col-sumsq
//        (+Q col-sum); seg2 (V) stores normal + row-sum. Q/K normal layout never exists.
template<int EPI>
__global__ __launch_bounds__(512)
void k_g256(const unsigned short* __restrict__ A,
            const unsigned short* __restrict__ Bt,
            void* __restrict__ O0, void* __restrict__ O1, void* __restrict__ O2,
            int K, long sA, long sB, long sC,
            const float* __restrict__ bias,
            float* __restrict__ r1, float* __restrict__ r2,
            float* __restrict__ r3, float* __restrict__ r4,
            const unsigned short* __restrict__ xh,
            const float* __restrict__ Vsum,
            const float* __restrict__ tailor,
            const float* __restrict__ gptr) {
  __shared__ __align__(16) unsigned short As[2][16384];   // 2 x 256x64 bf16 = 64 KiB
  __shared__ __align__(16) unsigned short Bs[2][16384];   // 64 KiB  (total 128 KiB)

  const int tid = threadIdx.x;
  const int wv = tid >> 6, lane = tid & 63;
  const int wr = wv >> 2, wcn = wv & 3;          // 2 x 4 wave grid
  const int l15 = lane & 15, lk = lane >> 4;

  // XCD-bijective swizzle over (x,y); nwg % 8 == 0 for all grids used
  const int nx = gridDim.x;
  const int nwg = nx * gridDim.y;
  const int lin = blockIdx.y * nx + blockIdx.x;
  const int cpx = nwg >> 3;
  const int wg = (lin & 7) * cpx + (lin >> 3);
  const int bn = wg % nx;
  const int bm = wg / nx;
  const int bz = blockIdx.z;

  const unsigned short* Ab = A + (long)bz * sA + (long)bm * 256 * K;
  const unsigned short* Bb = Bt + (long)bz * sB + (long)bn * 256 * K;

  // staging: quarter Q covers rows [64Q,64Q+64) x 64 k (8 KiB = 1 block-wide gload16).
  const int srow = tid >> 3;
  const int cg = (tid & 7) ^ (srow & 7);
  const long gOff = (long)srow * K + (long)cg * 8;   // + 64Q*K + t*64
  const int ldsb = wv * 512;

  // read side: frag (row r, kstep ks in {0,1}): elem = r*64 + ((ks*4+lk)^(r&7))*8; r&7==l15&7.
  const int sw0 = ((lk) ^ (l15 & 7)) * 8;
  const int sw1 = ((4 + lk) ^ (l15 & 7)) * 8;
  const int abase = (wr * 128 + l15) * 64;   // + i*1024 per 16-row step
  const int bbase = (wcn * 64 + l15) * 64;   // + j*1024

  f32x4 acc[8][4];
#pragma unroll
  for (int i = 0; i < 8; ++i)
#pragma unroll
    for (int j = 0; j < 4; ++j) acc[i][j] = (f32x4){0.f, 0.f, 0.f, 0.f};

  // prologue: tile 0 -> buf 0, in consumption-safe order B0,B1,B2,B3,A0,A2,A1,A3
  gload16(Bb + 0L * 64 * K + gOff, &Bs[0][0 * 4096 + ldsb]);
  gload16(Bb + 1L * 64 * K + gOff, &Bs[0][1 * 4096 + ldsb]);
  gload16(Bb + 2L * 64 * K + gOff, &Bs[0][2 * 4096 + ldsb]);
  gload16(Bb + 3L * 64 * K + gOff, &Bs[0][3 * 4096 + ldsb]);
  gload16(Ab + 0L * 64 * K + gOff, &As[0][0 * 4096 + ldsb]);
  gload16(Ab + 2L * 64 * K + gOff, &As[0][2 * 4096 + ldsb]);
  gload16(Ab + 1L * 64 * K + gOff, &As[0][1 * 4096 + ldsb]);
  gload16(Ab + 3L * 64 * K + gOff, &As[0][3 * 4096 + ldsb]);
  asm volatile("s_waitcnt vmcnt(2)" ::: "memory");   // A q1,q3 may lag (needed at ph2)
  SBAR;

  short8v Af[4][2], Bf[4][2];
  const int NT = K >> 6;

  for (int t = 0; t < NT; ++t) {
    const int cb = t & 1;
    const unsigned short* Asc = &As[cb][0];
    const unsigned short* Bsc = &Bs[cb][0];
    unsigned short* Asn = &As[cb ^ 1][0];
    unsigned short* Bsn = &Bs[cb ^ 1][0];
    const bool more = (t + 1 < NT);
    const long kb = (long)(t + 1) * 64;

    // ---------- ph0: read B nh0 + A mh0; stage B q0,q1
#pragma unroll
    for (int j = 0; j < 2; ++j) {
      Bf[j][0] = *(const short8v*)&Bsc[bbase + j * 1024 + sw0];
      Bf[j][1] = *(const short8v*)&Bsc[bbase + j * 1024 + sw1];
    }
#pragma unroll
    for (int i = 0; i < 4; ++i) {
      Af[i][0] = *(const short8v*)&Asc[abase + i * 1024 + sw0];
      Af[i][1] = *(const short8v*)&Asc[abase + i * 1024 + sw1];
    }
    if (more) {
      gload16(Bb + kb + gOff,             &Bsn[ldsb]);
      gload16(Bb + kb + gOff + 64L * K,   &Bsn[4096 + ldsb]);
    }
    SCHED0; SBAR; LGKM0; SCHED0;
    __builtin_amdgcn_s_setprio(1);
#pragma unroll
    for (int i = 0; i < 4; ++i)
#pragma unroll
      for (int j = 0; j < 2; ++j) {
        acc[i][j] = MFMA_BF16(Af[i][0], Bf[j][0], acc[i][j], 0, 0, 0);
        acc[i][j] = MFMA_BF16(Af[i][1], Bf[j][1], acc[i][j], 0, 0, 0);
      }
    __builtin_amdgcn_s_setprio(0);
    SCHED0; SBAR;

    // ---------- ph1: read B nh1; stage B q2,q3; counted vmcnt at end
#pragma unroll
    for (int j = 2; j < 4; ++j) {
      Bf[j][0] = *(const short8v*)&Bsc[bbase + j * 1024 + sw0];
      Bf[j][1] = *(const short8v*)&Bsc[bbase + j * 1024 + sw1];
    }
    if (more) {
      gload16(Bb + kb + gOff + 128L * K,  &Bsn[8192 + ldsb]);
      gload16(Bb + kb + gOff + 192L * K,  &Bsn[12288 + ldsb]);
    }
    SCHED0; SBAR; LGKM0; SCHED0;
    __builtin_amdgcn_s_setprio(1);
#pragma unroll
    for (int i = 0; i < 4; ++i)
#pragma unroll
      for (int j = 2; j < 4; ++j) {
        acc[i][j] = MFMA_BF16(Af[i][0], Bf[j][0], acc[i][j], 0, 0, 0);
        acc[i][j] = MFMA_BF16(Af[i][1], Bf[j][1], acc[i][j], 0, 0, 0);
      }
    __builtin_amdgcn_s_setprio(0);
    SCHED0;
    if (more) { asm volatile("s_waitcnt vmcnt(4)" ::: "memory"); }   // drains A q1,q3 of tile t
    else      { asm volatile("s_waitcnt vmcnt(0)" ::: "memory"); }
    SBAR;

    // ---------- ph2: read A mh1; stage A q0,q2
#pragma unroll
    for (int i = 0; i < 4; ++i) {
      Af[i][0] = *(const short8v*)&Asc[abase + (i + 4) * 1024 + sw0];
      Af[i][1] = *(const short8v*)&Asc[abase + (i + 4) * 1024 + sw1];
    }
    if (more) {
      gload16(Ab + kb + gOff,             &Asn[ldsb]);
      gload16(Ab + kb + gOff + 128L * K,  &Asn[8192 + ldsb]);
    }
    SCHED0; SBAR; LGKM0; SCHED0;
    __builtin_amdgcn_s_setprio(1);
#pragma unroll
    for (int i = 0; i < 4; ++i)
#pragma unroll
      for (int j = 0; j < 2; ++j) {
        acc[i + 4][j] = MFMA_BF16(Af[i][0], Bf[j][0], acc[i + 4][j], 0, 0, 0);
        acc[i + 4][j] = MFMA_BF16(Af[i][1], Bf[j][1], acc[i + 4][j], 0, 0, 0);
      }
    __builtin_amdgcn_s_setprio(0);
    SCHED0; SBAR;

    // ---------- ph3: no reads; stage A q1,q3; MFMA mh1 x nh1; counted vmcnt at end
    if (more) {
      gload16(Ab + kb + gOff + 64L * K,   &Asn[4096 + ldsb]);
      gload16(Ab + kb + gOff + 192L * K,  &Asn[12288 + ldsb]);
    }
    SCHED0; SBAR;
    __builtin_amdgcn_s_setprio(1);
#pragma unroll
    for (int i = 0; i < 4; ++i)
#pragma unroll
      for (int j = 2; j < 4; ++j) {
        acc[i + 4][j] = MFMA_BF16(Af[i][0], Bf[j][0], acc[i + 4][j], 0, 0, 0);
        acc[i + 4][j] = MFMA_BF16(Af[i][1], Bf[j][1], acc[i + 4][j], 0, 0, 0);
      }
    __builtin_amdgcn_s_setprio(0);
    SCHED0;
    if (more) { asm volatile("s_waitcnt vmcnt(2)" ::: "memory"); }   // allow A q1,q3 of t+1
    SBAR;
  }

  const int row0 = bm * 256 + wr * 128;
  const int col0 = bn * 256 + wcn * 64;

  if constexpr (EPI == 1) {
    float* Cb = (float*)O0 + (long)bz * sC;
    const float g = gptr[0];
#pragma unroll
    for (int i = 0; i < 8; ++i)
#pragma unroll
      for (int j = 0; j < 4; ++j) {
        const int col = col0 + j * 16 + l15;
        const float tl = tailor[bz * 1024 + col];
#pragma unroll
        for (int r = 0; r < 4; ++r) {
          const int row = row0 + i * 16 + lk * 4 + r;
          const long idx = ((long)bz * 2048 + row) * 1024 + col;
          Cb[(long)row * 1024 + col] = b2f(xh[idx]) + g * ((Vsum[bz * 2048 + row] + acc[i][j][r]) * tl);
        }
      }
  } else if constexpr (EPI == 4) {
    // S[p][l] = invq[p] * invk[l] * acc; bf16 store; Srow[p] += sum_l S[p][l] (scaled)
    unsigned short* Cb = (unsigned short*)O0 + (long)bz * sC;
    float ivk[4];
#pragma unroll
    for (int j = 0; j < 4; ++j) ivk[j] = r3[bz * 1024 + col0 + j * 16 + l15];
#pragma unroll
    for (int i = 0; i < 8; ++i) {
      float ivq[4];
#pragma unroll
      for (int r = 0; r < 4; ++r) ivq[r] = r2[bz * 1024 + row0 + i * 16 + lk * 4 + r];
#pragma unroll
      for (int r = 0; r < 4; ++r) {
        float sm = 0.f;
#pragma unroll
        for (int j = 0; j < 4; ++j) {
          const float v = acc[i][j][r] * ivq[r] * ivk[j];
          const int col = col0 + j * 16 + l15;
          const int row = row0 + i * 16 + lk * 4 + r;
          Cb[(long)row * 1024 + col] = f2b(v);
          sm += v;
        }
        sm = red16(sm);
        if (l15 == 0) {
          const int row = row0 + i * 16 + lk * 4 + r;
          atomicAdd(&r1[(long)bz * 1024 + row], sm);
        }
      }
    }
  } else {  // EPI == 5: merged QKV; Q/K stored TRANSPOSED, V normal
    const int seg = bn >> 2;             // 0=Q, 1=K, 2=V
    const int b = bm >> 3;               // batch (2048 rows per batch, 8 m-tiles)
    float bvj[4];
#pragma unroll
    for (int j = 0; j < 4; ++j) bvj[j] = bias[col0 + j * 16 + l15];
    const int colL0 = col0 & 1023;
    if (seg < 2) {
      // transposed store: QT/KT[b][p][m], m contiguous; lane's 4 r-values = consecutive m
      unsigned short* tp = (seg == 0 ? (unsigned short*)O0 : (unsigned short*)O1)
                           + (long)b * 2097152;   // 1024*2048 per batch
      const int mbase = (bm & 7) * 256 + wr * 128;
#pragma unroll
      for (int i = 0; i < 8; ++i)
#pragma unroll
        for (int j = 0; j < 4; ++j) {
          const int colL = colL0 + j * 16 + l15;
          us4 o;
#pragma unroll
          for (int r = 0; r < 4; ++r) o[r] = f2b(acc[i][j][r] + bvj[j]);
          *(us4*)&tp[(long)colL * 2048 + mbase + i * 16 + lk * 4] = o;
        }
      // per-column sumsq (and sum for Q) over this block's 256 rows
#pragma unroll
      for (int j = 0; j < 4; ++j) {
        const int colL = colL0 + j * 16 + l15;
        float ss = 0.f, sm = 0.f;
#pragma unroll
        for (int i = 0; i < 8; ++i)
#pragma unroll
          for (int r = 0; r < 4; ++r) {
            const float v = acc[i][j][r] + bvj[j];
            ss += v * v; sm += v;
          }
        ss = red4lk(ss);
        if (seg == 0) sm = red4lk(sm);
        if (lk == 0) {
          atomicAdd(&(seg == 0 ? r1 : r3)[(long)b * 1024 + colL], ss);
          if (seg == 0) atomicAdd(&r2[(long)b * 1024 + colL], sm);
        }
      }
    } else {
      unsigned short* outp = (unsigned short*)O2;
#pragma unroll
      for (int i = 0; i < 8; ++i)
#pragma unroll
        for (int j = 0; j < 4; ++j) {
          const int colL = colL0 + j * 16 + l15;
#pragma unroll
          for (int r = 0; r < 4; ++r) {
            const int row = row0 + i * 16 + lk * 4 + r;
            outp[(long)row * 1024 + colL] = f2b(acc[i][j][r] + bvj[j]);
          }
        }
      // per-row sum over this block's 256 cols (V row-sums)
#pragma unroll
      for (int i = 0; i < 8; ++i)
#pragma unroll
        for (int r = 0; r < 4; ++r) {
          float sm = 0.f;
#pragma unroll
          for (int j = 0; j < 4; ++j) sm += acc[i][j][r] + bvj[j];
          sm = red16(sm);
          if (l15 == 0) {
            const int row = row0 + i * 16 + lk * 4 + r;
            atomicAdd(&r4[row], sm);
          }
        }
    }
  }
}

extern "C" void kernel_launch(void* const* d_in, const int* in_sizes, int n_in,
                              void* d_out, int out_size, void* d_ws, size_t ws_size,
                              hipStream_t stream) {
  (void)in_sizes; (void)n_in; (void)out_size;
  const float* x     = (const float*)d_in[0];
  const float* Wq    = (const float*)d_in[1];
  const float* bq    = (const float*)d_in[2];
  const float* Wk    = (const float*)d_in[3];
  const float* bk    = (const float*)d_in[4];
  const float* Wv    = (const float*)d_in[5];
  const float* bv    = (const float*)d_in[6];
  const float* gamma = (const float*)d_in[7];

  // B=16, C=2048, L=D=1024
  const long NE = 16L * 2048 * 1024;
  const long BUF = NE * 2;                    // bytes per bf16 tensor

  char* w = (char*)d_ws;
  unsigned short* QT  = (unsigned short*)(w);            // [16][1024][2048] bf16
  unsigned short* KT  = (unsigned short*)(w + BUF);      // [16][1024][2048] bf16
  unsigned short* Vh  = (unsigned short*)(w + 2 * BUF);  // [32768][1024]
  unsigned short* xh  = (unsigned short*)(w + 3 * BUF);  // live to the end
  unsigned short* S   = (unsigned short*)(w + 4 * BUF);  // [16][1024][1024] (33.5 MB)
  size_t off = 4 * (size_t)BUF + (size_t)BUF / 2 + 4096;
  unsigned short* Wqkvh = (unsigned short*)(w + off); off += 3 * 2097152;  // Wq|Wk|Wv contiguous
  char* accbase = w + off;
  float* pq     = (float*)(w + off); off += 65536;       // col sumsq of Q  (16x1024)
  float* qsum   = (float*)(w + off); off += 65536;       // col sum of Q
  float* pk     = (float*)(w + off); off += 65536;       // col sumsq of K
  float* Vsum   = (float*)(w + off); off += 131072;      // row sum of V    (16x2048)
  float* Srow   = (float*)(w + off); off += 65536;       // row sum of scaled S (16x1024)
  const size_t accbytes = (size_t)(w + off - accbase);
  float* invq   = (float*)(w + off); off += 65536;
  float* invk   = (float*)(w + off); off += 65536;
  float* tailor = (float*)(w + off); off += 65536;
  float* bqkv   = (float*)(w + off); off += 12288;
  if (ws_size < off) return;

  // 0) zero atomic accumulators
  hipMemsetAsync(accbase, 0, accbytes, stream);

  // 1) casts + bias concat
  k_f32_to_bf16<<<dim3((unsigned)(NE / 1024)), 256, 0, stream>>>(x, xh, NE);
  k_f32_to_bf16<<<dim3(1024), 256, 0, stream>>>(Wq, Wqkvh, 1048576);
  k_f32_to_bf16<<<dim3(1024), 256, 0, stream>>>(Wk, Wqkvh + 1048576, 1048576);
  k_f32_to_bf16<<<dim3(1024), 256, 0, stream>>>(Wv, Wqkvh + 2097152, 1048576);
  k_bias_cat<<<dim3(12), 256, 0, stream>>>(bq, bk, bv, bqkv);

  // 2) merged QKV GEMM: M=32768, N=3072, K=1024; Q,K stored transposed + fused reductions
  k_g256<5><<<dim3(12, 128, 1), 512, 0, stream>>>(
      xh, Wqkvh, QT, KT, Vh, 1024, 0, 0, 0, bqkv,
      pq, qsum, pk, Vsum, nullptr, nullptr, nullptr, nullptr);

  // 3) inverse norms
  k_norms_fin<<<dim3(64), 256, 0, stream>>>(pq, pk, invq, invk);

  // 4) S = invq.(QT x KT^T).invk per batch (M=N=1024, K=2048) + scaled row sums
  k_g256<4><<<dim3(4, 4, 16), 512, 0, stream>>>(
      QT, KT, S, nullptr, nullptr, 2048, 1024L * 2048, 1024L * 2048, 1024L * 1024,
      nullptr, Srow, invq, invk, nullptr, nullptr, nullptr, nullptr, nullptr);

  // 5) tailor
  k_tailor_fin<<<dim3(64), 256, 0, stream>>>(Srow, invq, qsum, tailor);

  // 6) out = xh + gamma*(Vsum + V x S^T) * tailor   (M=2048/batch, N=1024, K=1024)
  k_g256<1><<<dim3(4, 8, 16), 512, 0, stream>>>(
      Vh, S, d_out, nullptr, nullptr, 1024, 2048L * 1024, 1024L * 1024, 2048L * 1024,
      nullptr, nullptr, nullptr, nullptr, nullptr, xh, Vsum, tailor, gamma);
}

// Round 11
// 468.740 us; speedup vs baseline: 1.3629x; 1.0650x over previous
//
#include <hip/hip_runtime.h>
#include <cstdint>

#define DEV static __device__ __forceinline__

typedef __attribute__((ext_vector_type(8))) short short8v;     // 8 x bf16 bits
typedef __attribute__((ext_vector_type(4))) float f32x4;
typedef __attribute__((ext_vector_type(4))) float fl4;
typedef __attribute__((ext_vector_type(4))) unsigned short us4;
typedef __attribute__((ext_vector_type(8))) unsigned short us8;

DEV float b2f(unsigned short u) {
  union { unsigned int i; float f; } c; c.i = ((unsigned int)u) << 16; return c.f;
}
DEV unsigned short f2b(float f) {   // RNE float -> bf16 bits
  union { float f; unsigned int i; } c; c.f = f;
  unsigned int u = c.i;
  u += 0x7fffu + ((u >> 16) & 1u);
  return (unsigned short)(u >> 16);
}

DEV void gload16(const void* g, void* l) {  // async global->LDS, 16B/lane
  __builtin_amdgcn_global_load_lds(
      (const __attribute__((address_space(1))) unsigned int*)g,
      (__attribute__((address_space(3))) unsigned int*)l, 16, 0, 0);
}

DEV float red16(float v) {  // reduce across 16 lanes sharing lk (xor low 4 bits)
  v += __shfl_xor(v, 1); v += __shfl_xor(v, 2);
  v += __shfl_xor(v, 4); v += __shfl_xor(v, 8);
  return v;
}
DEV float red4lk(float v) { // reduce across the 4 lk groups (xor bits 4,5)
  v += __shfl_xor(v, 16); v += __shfl_xor(v, 32);
  return v;
}

// ---------------- elementwise f32 -> bf16 ----------------
__global__ __launch_bounds__(256) void k_f32_to_bf16(const float* __restrict__ src,
                                                     unsigned short* __restrict__ dst, long n) {
  long i = ((long)blockIdx.x * 256 + threadIdx.x) * 4;
  if (i >= n) return;
  fl4 v = *(const fl4*)(src + i);
  us4 o;
  o[0] = f2b(v[0]); o[1] = f2b(v[1]); o[2] = f2b(v[2]); o[3] = f2b(v[3]);
  *(us4*)(dst + i) = o;
}

// ---------------- concat biases into 3072-float buffer ----------------
__global__ __launch_bounds__(256) void k_bias_cat(const float* __restrict__ bq,
                                                  const float* __restrict__ bk,
                                                  const float* __restrict__ bv,
                                                  float* __restrict__ o) {
  const int t = blockIdx.x * 256 + threadIdx.x;   // 3072
  o[t] = t < 1024 ? bq[t] : (t < 2048 ? bk[t - 1024] : bv[t - 2048]);
}

// ---------------- finalize inverse norms ----------------
__global__ __launch_bounds__(256) void k_norms_fin(const float* __restrict__ pq,
                                                   const float* __restrict__ pk,
                                                   float* __restrict__ invq, float* __restrict__ invk) {
  const int gid = blockIdx.x * 256 + threadIdx.x;   // 16384
  invq[gid] = rsqrtf(pq[gid]);
  invk[gid] = rsqrtf(pk[gid]);
}

// ---------------- finalize tailor: 1/(L + rowsum(S) + eps*invq*colsum(Q)) ----------------
__global__ __launch_bounds__(256) void k_tailor_fin(const float* __restrict__ Srow,
                                                    const float* __restrict__ invq,
                                                    const float* __restrict__ qsum,
                                                    float* __restrict__ tailor) {
  const int gid = blockIdx.x * 256 + threadIdx.x;   // 16384
  tailor[gid] = 1.0f / (1024.0f + Srow[gid] + 1e-6f * invq[gid] * qsum[gid]);
}

#define MFMA_BF16 __builtin_amdgcn_mfma_f32_16x16x32_bf16
#define SCHED0 __builtin_amdgcn_sched_barrier(0)
#define SBAR   __builtin_amdgcn_s_barrier()
#define LGKM0  asm volatile("s_waitcnt lgkmcnt(0)" ::: "memory")

// ---------------- 256x256 NT GEMM, BK=64, 8 waves (2Mx4N), m201-style 4-phase/K-tile ----
// K-loop identical to R9/R10 (verified). NEW: all epilogues go through an LDS roundtrip
// (K-loop LDS is dead after the final barrier -> 128 KiB scratch): stage fragments with a
// cell-XOR swizzle (16B cells, cell ^= row&15, involution both sides), barrier, read back
// full rows -> 16B-coalesced global stores (and, for EPI 1, coalesced xh/tailor loads).
// Reductions/atomics stay pre-stage (in-register, unchanged).
// EPI 1: final fused fp32 epilogue (residual bf16 xh, Vsum, tailor, gamma), 2 fp32 halves.
// EPI 4: S-GEMM: scaled bf16 S + per-row atomic sums (r1=Srow, r2=invq, r3=invk).
// EPI 5: merged QKV: Q/K stored TRANSPOSED via roundtrip + col reductions; V normal + row sums.
template<int EPI>
__global__ __launch_bounds__(512)
void k_g256(const unsigned short* __restrict__ A,
            const unsigned short* __restrict__ Bt,
            void* __restrict__ O0, void* __restrict__ O1, void* __restrict__ O2,
            int K, long sA, long sB, long sC,
            const float* __restrict__ bias,
            float* __restrict__ r1, float* __restrict__ r2,
            float* __restrict__ r3, float* __restrict__ r4,
            const unsigned short* __restrict__ xh,
            const float* __restrict__ Vsum,
            const float* __restrict__ tailor,
            const float* __restrict__ gptr) {
  __shared__ __align__(16) unsigned short LDSU[65536];   // 128 KiB: K-loop dbufs, then scratch

  const int tid = threadIdx.x;
  const int wv = tid >> 6, lane = tid & 63;
  const int wr = wv >> 2, wcn = wv & 3;          // 2 x 4 wave grid
  const int l15 = lane & 15, lk = lane >> 4;

  // XCD-bijective swizzle over (x,y); nwg % 8 == 0 for all grids used
  const int nx = gridDim.x;
  const int nwg = nx * gridDim.y;
  const int lin = blockIdx.y * nx + blockIdx.x;
  const int cpx = nwg >> 3;
  const int wg = (lin & 7) * cpx + (lin >> 3);
  const int bn = wg % nx;
  const int bm = wg / nx;
  const int bz = blockIdx.z;

  const unsigned short* Ab = A + (long)bz * sA + (long)bm * 256 * K;
  const unsigned short* Bb = Bt + (long)bz * sB + (long)bn * 256 * K;

  // staging: quarter Q covers rows [64Q,64Q+64) x 64 k (8 KiB = 1 block-wide gload16).
  const int srow = tid >> 3;
  const int cg = (tid & 7) ^ (srow & 7);
  const long gOff = (long)srow * K + (long)cg * 8;   // + 64Q*K + t*64
  const int ldsb = wv * 512;

  // read side: frag (row r, kstep ks in {0,1}): elem = r*64 + ((ks*4+lk)^(r&7))*8; r&7==l15&7.
  const int sw0 = ((lk) ^ (l15 & 7)) * 8;
  const int sw1 = ((4 + lk) ^ (l15 & 7)) * 8;
  const int abase = (wr * 128 + l15) * 64;   // + i*1024 per 16-row step
  const int bbase = (wcn * 64 + l15) * 64;   // + j*1024

  f32x4 acc[8][4];
#pragma unroll
  for (int i = 0; i < 8; ++i)
#pragma unroll
    for (int j = 0; j < 4; ++j) acc[i][j] = (f32x4){0.f, 0.f, 0.f, 0.f};

  // prologue: tile 0 -> buf 0, in consumption-safe order B0,B1,B2,B3,A0,A2,A1,A3
  {
    unsigned short* A0 = LDSU;
    unsigned short* B0 = LDSU + 32768;
    gload16(Bb + 0L * 64 * K + gOff, &B0[0 * 4096 + ldsb]);
    gload16(Bb + 1L * 64 * K + gOff, &B0[1 * 4096 + ldsb]);
    gload16(Bb + 2L * 64 * K + gOff, &B0[2 * 4096 + ldsb]);
    gload16(Bb + 3L * 64 * K + gOff, &B0[3 * 4096 + ldsb]);
    gload16(Ab + 0L * 64 * K + gOff, &A0[0 * 4096 + ldsb]);
    gload16(Ab + 2L * 64 * K + gOff, &A0[2 * 4096 + ldsb]);
    gload16(Ab + 1L * 64 * K + gOff, &A0[1 * 4096 + ldsb]);
    gload16(Ab + 3L * 64 * K + gOff, &A0[3 * 4096 + ldsb]);
  }
  asm volatile("s_waitcnt vmcnt(2)" ::: "memory");   // A q1,q3 may lag (needed at ph2)
  SBAR;

  short8v Af[4][2], Bf[4][2];
  const int NT = K >> 6;

  for (int t = 0; t < NT; ++t) {
    const int cb = t & 1;
    const unsigned short* Asc = LDSU + cb * 16384;
    const unsigned short* Bsc = LDSU + 32768 + cb * 16384;
    unsigned short* Asn = LDSU + (cb ^ 1) * 16384;
    unsigned short* Bsn = LDSU + 32768 + (cb ^ 1) * 16384;
    const bool more = (t + 1 < NT);
    const long kb = (long)(t + 1) * 64;

    // ---------- ph0: read B nh0 + A mh0; stage B q0,q1
#pragma unroll
    for (int j = 0; j < 2; ++j) {
      Bf[j][0] = *(const short8v*)&Bsc[bbase + j * 1024 + sw0];
      Bf[j][1] = *(const short8v*)&Bsc[bbase + j * 1024 + sw1];
    }
#pragma unroll
    for (int i = 0; i < 4; ++i) {
      Af[i][0] = *(const short8v*)&Asc[abase + i * 1024 + sw0];
      Af[i][1] = *(const short8v*)&Asc[abase + i * 1024 + sw1];
    }
    if (more) {
      gload16(Bb + kb + gOff,             &Bsn[ldsb]);
      gload16(Bb + kb + gOff + 64L * K,   &Bsn[4096 + ldsb]);
    }
    SCHED0; SBAR; LGKM0; SCHED0;
    __builtin_amdgcn_s_setprio(1);
#pragma unroll
    for (int i = 0; i < 4; ++i)
#pragma unroll
      for (int j = 0; j < 2; ++j) {
        acc[i][j] = MFMA_BF16(Af[i][0], Bf[j][0], acc[i][j], 0, 0, 0);
        acc[i][j] = MFMA_BF16(Af[i][1], Bf[j][1], acc[i][j], 0, 0, 0);
      }
    __builtin_amdgcn_s_setprio(0);
    SCHED0; SBAR;

    // ---------- ph1: read B nh1; stage B q2,q3; counted vmcnt at end
#pragma unroll
    for (int j = 2; j < 4; ++j) {
      Bf[j][0] = *(const short8v*)&Bsc[bbase + j * 1024 + sw0];
      Bf[j][1] = *(const short8v*)&Bsc[bbase + j * 1024 + sw1];
    }
    if (more) {
      gload16(Bb + kb + gOff + 128L * K,  &Bsn[8192 + ldsb]);
      gload16(Bb + kb + gOff + 192L * K,  &Bsn[12288 + ldsb]);
    }
    SCHED0; SBAR; LGKM0; SCHED0;
    __builtin_amdgcn_s_setprio(1);
#pragma unroll
    for (int i = 0; i < 4; ++i)
#pragma unroll
      for (int j = 2; j < 4; ++j) {
        acc[i][j] = MFMA_BF16(Af[i][0], Bf[j][0], acc[i][j], 0, 0, 0);
        acc[i][j] = MFMA_BF16(Af[i][1], Bf[j][1], acc[i][j], 0, 0, 0);
      }
    __builtin_amdgcn_s_setprio(0);
    SCHED0;
    if (more) { asm volatile("s_waitcnt vmcnt(4)" ::: "memory"); }   // drains A q1,q3 of tile t
    else      { asm volatile("s_waitcnt vmcnt(0)" ::: "memory"); }
    SBAR;

    // ---------- ph2: read A mh1; stage A q0,q2
#pragma unroll
    for (int i = 0; i < 4; ++i) {
      Af[i][0] = *(const short8v*)&Asc[abase + (i + 4) * 1024 + sw0];
      Af[i][1] = *(const short8v*)&Asc[abase + (i + 4) * 1024 + sw1];
    }
    if (more) {
      gload16(Ab + kb + gOff,             &Asn[ldsb]);
      gload16(Ab + kb + gOff + 128L * K,  &Asn[8192 + ldsb]);
    }
    SCHED0; SBAR; LGKM0; SCHED0;
    __builtin_amdgcn_s_setprio(1);
#pragma unroll
    for (int i = 0; i < 4; ++i)
#pragma unroll
      for (int j = 0; j < 2; ++j) {
        acc[i + 4][j] = MFMA_BF16(Af[i][0], Bf[j][0], acc[i + 4][j], 0, 0, 0);
        acc[i + 4][j] = MFMA_BF16(Af[i][1], Bf[j][1], acc[i + 4][j], 0, 0, 0);
      }
    __builtin_amdgcn_s_setprio(0);
    SCHED0; SBAR;

    // ---------- ph3: no reads; stage A q1,q3; MFMA mh1 x nh1; counted vmcnt at end
    if (more) {
      gload16(Ab + kb + gOff + 64L * K,   &Asn[4096 + ldsb]);
      gload16(Ab + kb + gOff + 192L * K,  &Asn[12288 + ldsb]);
    }
    SCHED0; SBAR;
    __builtin_amdgcn_s_setprio(1);
#pragma unroll
    for (int i = 0; i < 4; ++i)
#pragma unroll
      for (int j = 2; j < 4; ++j) {
        acc[i + 4][j] = MFMA_BF16(Af[i][0], Bf[j][0], acc[i + 4][j], 0, 0, 0);
        acc[i + 4][j] = MFMA_BF16(Af[i][1], Bf[j][1], acc[i + 4][j], 0, 0, 0);
      }
    __builtin_amdgcn_s_setprio(0);
    SCHED0;
    if (more) { asm volatile("s_waitcnt vmcnt(2)" ::: "memory"); }   // allow A q1,q3 of t+1
    SBAR;
  }
  // after this barrier all waves are done with the K-loop LDS -> reuse as scratch

  const int row0 = bm * 256 + wr * 128;
  const int col0 = bn * 256 + wcn * 64;
  unsigned short* sc = LDSU;       // [256 rows][256 cols] bf16, cell-swizzled
  float* scf = (float*)LDSU;       // [128 rows][256 cols] fp32, cell-swizzled

  if constexpr (EPI == 1) {
    float* Cb = (float*)O0 + (long)bz * sC;
    const float g = gptr[0];
#pragma unroll
    for (int h = 0; h < 2; ++h) {
      if (wr == h) {
#pragma unroll
        for (int i = 0; i < 8; ++i)
#pragma unroll
          for (int j = 0; j < 4; ++j) {
            const int col = wcn * 64 + j * 16 + l15;
            const int cc = col >> 2, c3 = col & 3;
#pragma unroll
            for (int r = 0; r < 4; ++r) {
              const int rl = i * 16 + lk * 4 + r;     // [0,128)
              scf[rl * 256 + ((cc ^ (rl & 15)) << 2) + c3] = acc[i][j][r];
            }
          }
      }
      SBAR;
#pragma unroll
      for (int it = 0; it < 16; ++it) {
        const int rl = it * 8 + wv;                    // [0,128)
        const int rg = bm * 256 + h * 128 + rl;        // [0,2048)
        const int c = lane;                            // f32 cell [0,64)
        fl4 a4 = *(const fl4*)&scf[rl * 256 + ((c ^ (rl & 15)) << 2)];
        const int cg = bn * 256 + c * 4;
        us4 xv = *(const us4*)&xh[((long)bz * 2048 + rg) * 1024 + cg];
        fl4 tl = *(const fl4*)&tailor[bz * 1024 + cg];
        const float vs = Vsum[bz * 2048 + rg];
        fl4 o;
#pragma unroll
        for (int q = 0; q < 4; ++q) o[q] = b2f(xv[q]) + g * ((vs + a4[q]) * tl[q]);
        *(fl4*)&Cb[(long)rg * 1024 + cg] = o;
      }
      if (h == 0) SBAR;
    }
  } else if constexpr (EPI == 4) {
    // S[p][l] = invq[p]*invk[l]*acc; Srow[p] += scaled row sum; roundtrip -> us8 stores
    unsigned short* Cb = (unsigned short*)O0 + (long)bz * sC;
    float ivk[4];
#pragma unroll
    for (int j = 0; j < 4; ++j) ivk[j] = r3[bz * 1024 + col0 + j * 16 + l15];
#pragma unroll
    for (int i = 0; i < 8; ++i) {
      float ivq[4];
#pragma unroll
      for (int r = 0; r < 4; ++r) ivq[r] = r2[bz * 1024 + row0 + i * 16 + lk * 4 + r];
#pragma unroll
      for (int r = 0; r < 4; ++r) {
        const int rl = wr * 128 + i * 16 + lk * 4 + r;   // [0,256)
        float sm = 0.f;
#pragma unroll
        for (int j = 0; j < 4; ++j) {
          const float v = acc[i][j][r] * ivq[r] * ivk[j];
          sm += v;
          const int col = wcn * 64 + j * 16 + l15;
          sc[rl * 256 + (((col >> 3) ^ (rl & 15)) << 3) + (col & 7)] = f2b(v);
        }
        sm = red16(sm);
        if (l15 == 0) atomicAdd(&r1[(long)bz * 1024 + row0 + i * 16 + lk * 4 + r], sm);
      }
    }
    SBAR;
#pragma unroll
    for (int it = 0; it < 16; ++it) {
      const int rl = it * 16 + wv * 2 + (lane >> 5);    // [0,256)
      const int c = lane & 31;
      us8 v = *(const us8*)&sc[rl * 256 + ((c ^ (rl & 15)) << 3)];
      *(us8*)&Cb[(long)(bm * 256 + rl) * 1024 + bn * 256 + c * 8] = v;
    }
  } else {  // EPI == 5: merged QKV
    const int seg = bn >> 2;             // 0=Q, 1=K, 2=V
    const int b = bm >> 3;               // batch
    float bvj[4];
#pragma unroll
    for (int j = 0; j < 4; ++j) bvj[j] = bias[col0 + j * 16 + l15];
    const int colL0 = col0 & 1023;
    if (seg < 2) {
      // stage transposed: p = local col [0,256), m = local row [0,256)
#pragma unroll
      for (int i = 0; i < 8; ++i)
#pragma unroll
        for (int j = 0; j < 4; ++j) {
          const int p = wcn * 64 + j * 16 + l15;
          const int m = wr * 128 + i * 16 + lk * 4;    // aligned 4
          us4 o;
#pragma unroll
          for (int r = 0; r < 4; ++r) o[r] = f2b(acc[i][j][r] + bvj[j]);
          *(us4*)&sc[p * 256 + (((m >> 3) ^ (p & 15)) << 3) + (m & 7)] = o;
        }
      // col reductions (pre-stage values, in-register)
#pragma unroll
      for (int j = 0; j < 4; ++j) {
        const int colL = colL0 + j * 16 + l15;
        float ss = 0.f, sm = 0.f;
#pragma unroll
        for (int i = 0; i < 8; ++i)
#pragma unroll
          for (int r = 0; r < 4; ++r) {
            const float v = acc[i][j][r] + bvj[j];
            ss += v * v; sm += v;
          }
        ss = red4lk(ss);
        if (seg == 0) sm = red4lk(sm);
        if (lk == 0) {
          atomicAdd(&(seg == 0 ? r1 : r3)[(long)b * 1024 + colL], ss);
          if (seg == 0) atomicAdd(&r2[(long)b * 1024 + colL], sm);
        }
      }
      SBAR;
      unsigned short* tp = (seg == 0 ? (unsigned short*)O0 : (unsigned short*)O1)
                           + (long)b * 2097152;        // 1024*2048 per batch
      const int P0 = (bn & 3) * 256;
      const int M0 = (bm & 7) * 256;
#pragma unroll
      for (int it = 0; it < 16; ++it) {
        const int p = it * 16 + wv * 2 + (lane >> 5);  // [0,256)
        const int c = lane & 31;
        us8 v = *(const us8*)&sc[p * 256 + ((c ^ (p & 15)) << 3)];
        *(us8*)&tp[(long)(P0 + p) * 2048 + M0 + c * 8] = v;
      }
    } else {
      // V: stage normal layout + row sums
#pragma unroll
      for (int i = 0; i < 8; ++i)
#pragma unroll
        for (int r = 0; r < 4; ++r) {
          const int rl = wr * 128 + i * 16 + lk * 4 + r;  // [0,256)
          float sm = 0.f;
#pragma unroll
          for (int j = 0; j < 4; ++j) {
            const float v = acc[i][j][r] + bvj[j];
            sm += v;
            const int col = wcn * 64 + j * 16 + l15;
            sc[rl * 256 + (((col >> 3) ^ (rl & 15)) << 3) + (col & 7)] = f2b(v);
          }
          sm = red16(sm);
          if (l15 == 0) atomicAdd(&r4[row0 + i * 16 + lk * 4 + r], sm);
        }
      SBAR;
      unsigned short* outp = (unsigned short*)O2;
      const int C0 = (bn & 3) * 256;
#pragma unroll
      for (int it = 0; it < 16; ++it) {
        const int rl = it * 16 + wv * 2 + (lane >> 5);
        const int c = lane & 31;
        us8 v = *(const us8*)&sc[rl * 256 + ((c ^ (rl & 15)) << 3)];
        *(us8*)&outp[(long)(bm * 256 + rl) * 1024 + C0 + c * 8] = v;
      }
    }
  }
}

extern "C" void kernel_launch(void* const* d_in, const int* in_sizes, int n_in,
                              void* d_out, int out_size, void* d_ws, size_t ws_size,
                              hipStream_t stream) {
  (void)in_sizes; (void)n_in; (void)out_size;
  const float* x     = (const float*)d_in[0];
  const float* Wq    = (const float*)d_in[1];
  const float* bq    = (const float*)d_in[2];
  const float* Wk    = (const float*)d_in[3];
  const float* bk    = (const float*)d_in[4];
  const float* Wv    = (const float*)d_in[5];
  const float* bv    = (const float*)d_in[6];
  const float* gamma = (const float*)d_in[7];

  // B=16, C=2048, L=D=1024
  const long NE = 16L * 2048 * 1024;
  const long BUF = NE * 2;                    // bytes per bf16 tensor

  char* w = (char*)d_ws;
  unsigned short* QT  = (unsigned short*)(w);            // [16][1024][2048] bf16
  unsigned short* KT  = (unsigned short*)(w + BUF);      // [16][1024][2048] bf16
  unsigned short* Vh  = (unsigned short*)(w + 2 * BUF);  // [32768][1024]
  unsigned short* xh  = (unsigned short*)(w + 3 * BUF);  // live to the end
  unsigned short* S   = (unsigned short*)(w + 4 * BUF);  // [16][1024][1024] (33.5 MB)
  size_t off = 4 * (size_t)BUF + (size_t)BUF / 2 + 4096;
  unsigned short* Wqkvh = (unsigned short*)(w + off); off += 3 * 2097152;  // Wq|Wk|Wv contiguous
  char* accbase = w + off;
  float* pq     = (float*)(w + off); off += 65536;       // col sumsq of Q  (16x1024)
  float* qsum   = (float*)(w + off); off += 65536;       // col sum of Q
  float* pk     = (float*)(w + off); off += 65536;       // col sumsq of K
  float* Vsum   = (float*)(w + off); off += 131072;      // row sum of V    (16x2048)
  float* Srow   = (float*)(w + off); off += 65536;       // row sum of scaled S (16x1024)
  const size_t accbytes = (size_t)(w + off - accbase);
  float* invq   = (float*)(w + off); off += 65536;
  float* invk   = (float*)(w + off); off += 65536;
  float* tailor = (float*)(w + off); off += 65536;
  float* bqkv   = (float*)(w + off); off += 12288;
  if (ws_size < off) return;

  // 0) zero atomic accumulators
  hipMemsetAsync(accbase, 0, accbytes, stream);

  // 1) casts + bias concat
  k_f32_to_bf16<<<dim3((unsigned)(NE / 1024)), 256, 0, stream>>>(x, xh, NE);
  k_f32_to_bf16<<<dim3(1024), 256, 0, stream>>>(Wq, Wqkvh, 1048576);
  k_f32_to_bf16<<<dim3(1024), 256, 0, stream>>>(Wk, Wqkvh + 1048576, 1048576);
  k_f32_to_bf16<<<dim3(1024), 256, 0, stream>>>(Wv, Wqkvh + 2097152, 1048576);
  k_bias_cat<<<dim3(12), 256, 0, stream>>>(bq, bk, bv, bqkv);

  // 2) merged QKV GEMM: M=32768, N=3072, K=1024; Q,K stored transposed + fused reductions
  k_g256<5><<<dim3(12, 128, 1), 512, 0, stream>>>(
      xh, Wqkvh, QT, KT, Vh, 1024, 0, 0, 0, bqkv,
      pq, qsum, pk, Vsum, nullptr, nullptr, nullptr, nullptr);

  // 3) inverse norms
  k_norms_fin<<<dim3(64), 256, 0, stream>>>(pq, pk, invq, invk);

  // 4) S = invq.(QT x KT^T).invk per batch (M=N=1024, K=2048) + scaled row sums
  k_g256<4><<<dim3(4, 4, 16), 512, 0, stream>>>(
      QT, KT, S, nullptr, nullptr, 2048, 1024L * 2048, 1024L * 2048, 1024L * 1024,
      nullptr, Srow, invq, invk, nullptr, nullptr, nullptr, nullptr, nullptr);

  // 5) tailor
  k_tailor_fin<<<dim3(64), 256, 0, stream>>>(Srow, invq, qsum, tailor);

  // 6) out = xh + gamma*(Vsum + V x S^T) * tailor   (M=2048/batch, N=1024, K=1024)
  k_g256<1><<<dim3(4, 8, 16), 512, 0, stream>>>(
      Vh, S, d_out, nullptr, nullptr, 1024, 2048L * 1024, 1024L * 1024, 2048L * 1024,
      nullptr, nullptr, nullptr, nullptr, nullptr, xh, Vsum, tailor, gamma);
}

// Round 12
// 465.977 us; speedup vs baseline: 1.3710x; 1.0059x over previous
//
#include <hip/hip_runtime.h>
#include <cstdint>

#define DEV static __device__ __forceinline__

typedef __attribute__((ext_vector_type(8))) short short8v;     // 8 x bf16 bits
typedef __attribute__((ext_vector_type(4))) float f32x4;
typedef __attribute__((ext_vector_type(4))) float fl4;
typedef __attribute__((ext_vector_type(4))) unsigned short us4;
typedef __attribute__((ext_vector_type(8))) unsigned short us8;

DEV float b2f(unsigned short u) {
  union { unsigned int i; float f; } c; c.i = ((unsigned int)u) << 16; return c.f;
}
DEV unsigned short f2b(float f) {   // RNE float -> bf16 bits
  union { float f; unsigned int i; } c; c.f = f;
  unsigned int u = c.i;
  u += 0x7fffu + ((u >> 16) & 1u);
  return (unsigned short)(u >> 16);
}

DEV void gload16(const void* g, void* l) {  // async global->LDS, 16B/lane
  __builtin_amdgcn_global_load_lds(
      (const __attribute__((address_space(1))) unsigned int*)g,
      (__attribute__((address_space(3))) unsigned int*)l, 16, 0, 0);
}

DEV float red16(float v) {  // reduce across 16 lanes sharing lk (xor low 4 bits)
  v += __shfl_xor(v, 1); v += __shfl_xor(v, 2);
  v += __shfl_xor(v, 4); v += __shfl_xor(v, 8);
  return v;
}
DEV float red4lk(float v) { // reduce across the 4 lk groups (xor bits 4,5)
  v += __shfl_xor(v, 16); v += __shfl_xor(v, 32);
  return v;
}

// ---------------- elementwise f32 -> bf16 ----------------
__global__ __launch_bounds__(256) void k_f32_to_bf16(const float* __restrict__ src,
                                                     unsigned short* __restrict__ dst, long n) {
  long i = ((long)blockIdx.x * 256 + threadIdx.x) * 4;
  if (i >= n) return;
  fl4 v = *(const fl4*)(src + i);
  us4 o;
  o[0] = f2b(v[0]); o[1] = f2b(v[1]); o[2] = f2b(v[2]); o[3] = f2b(v[3]);
  *(us4*)(dst + i) = o;
}

// ---------------- concat biases into 3072-float buffer ----------------
__global__ __launch_bounds__(256) void k_bias_cat(const float* __restrict__ bq,
                                                  const float* __restrict__ bk,
                                                  const float* __restrict__ bv,
                                                  float* __restrict__ o) {
  const int t = blockIdx.x * 256 + threadIdx.x;   // 3072
  o[t] = t < 1024 ? bq[t] : (t < 2048 ? bk[t - 1024] : bv[t - 2048]);
}

// ---------------- finalize inverse norms ----------------
__global__ __launch_bounds__(256) void k_norms_fin(const float* __restrict__ pq,
                                                   const float* __restrict__ pk,
                                                   float* __restrict__ invq, float* __restrict__ invk) {
  const int gid = blockIdx.x * 256 + threadIdx.x;   // 16384
  invq[gid] = rsqrtf(pq[gid]);
  invk[gid] = rsqrtf(pk[gid]);
}

// ---------------- finalize tailor: 1/(L + rowsum(S) + eps*invq*colsum(Q)) ----------------
__global__ __launch_bounds__(256) void k_tailor_fin(const float* __restrict__ Srow,
                                                    const float* __restrict__ invq,
                                                    const float* __restrict__ qsum,
                                                    float* __restrict__ tailor) {
  const int gid = blockIdx.x * 256 + threadIdx.x;   // 16384
  tailor[gid] = 1.0f / (1024.0f + Srow[gid] + 1e-6f * invq[gid] * qsum[gid]);
}

#define MFMA_BF16 __builtin_amdgcn_mfma_f32_16x16x32_bf16
#define SBAR   __builtin_amdgcn_s_barrier()

// ---------------- 256x256 NT GEMM, BK=32, 8 waves (2Mx4N), free-run interior ----------
// Topology change (this round's single variable): 4 LDS K-tile buffers (128 KiB); at tile
// t stage tile t+2 (4 gloads); per-tile counted s_waitcnt vmcnt(4) (0 only at tail);
// s_barrier ONLY every 2nd tile. Interior has NO barriers/pins: the compiler's per-use
// counted lgkm waits handle read->MFMA deps per wave, so the 2 waves/SIMD skew and
// anti-correlate (one reads LDS while the other MFMAs; setprio biases the MFMA wave).
// Buffer safety under <=1-tile skew (enforced by the 2-tile barrier window): reader of
// tile u uses buf u&3; stagers write (u+2..u+3)&3 and prior tiles' bufs only after the
// even-tile barrier proves all waves passed them. All-distinct mod 4. [proof in journal]
// LDS chunk-swizzle (verified 0-conflict) + XCD-bijective block swizzle carried over.
// Epilogues (LDS-roundtrip, verified R11) carried over verbatim.
// EPI 1: final fused fp32 epilogue.  EPI 4: scaled-S + row sums.  EPI 5: merged QKV.
template<int EPI>
__global__ __launch_bounds__(512)
void k_g256(const unsigned short* __restrict__ A,
            const unsigned short* __restrict__ Bt,
            void* __restrict__ O0, void* __restrict__ O1, void* __restrict__ O2,
            int K, long sA, long sB, long sC,
            const float* __restrict__ bias,
            float* __restrict__ r1, float* __restrict__ r2,
            float* __restrict__ r3, float* __restrict__ r4,
            const unsigned short* __restrict__ xh,
            const float* __restrict__ Vsum,
            const float* __restrict__ tailor,
            const float* __restrict__ gptr) {
  __shared__ __align__(16) unsigned short LDSU[65536];   // 128 KiB: 4 K-tile bufs, then scratch

  const int tid = threadIdx.x;
  const int wv = tid >> 6, lane = tid & 63;
  const int wr = wv >> 2, wcn = wv & 3;          // 2 x 4 wave grid
  const int l15 = lane & 15, lk = lane >> 4;

  // XCD-bijective swizzle over (x,y); nwg % 8 == 0 for all grids used
  const int nx = gridDim.x;
  const int nwg = nx * gridDim.y;
  const int lin = blockIdx.y * nx + blockIdx.x;
  const int cpx = nwg >> 3;
  const int wg = (lin & 7) * cpx + (lin >> 3);
  const int bn = wg % nx;
  const int bm = wg / nx;
  const int bz = blockIdx.z;

  const unsigned short* Ab = A + (long)bz * sA + (long)bm * 256 * K;
  const unsigned short* Bb = Bt + (long)bz * sB + (long)bn * 256 * K;

  // staging (BK=32): thread tid covers row tid>>2 (q adds 128), physical chunk tid&3,
  // pre-swizzled global chunk = (tid&3) ^ ((row>>1)&3) = (tid&3) ^ ((tid>>3)&3).
  const int scsw = (tid & 3) ^ ((tid >> 3) & 3);
  const long gOff = (long)(tid >> 2) * K + (long)scsw * 8;   // + 128q*K + t*32
  const int ldsb = wv * 512;                                  // + q*4096

  // read-side swizzle: chunk' = lk ^ ((row>>1)&3); row bits 1-2 come from l15 only.
  const int rdsw = (lk ^ ((l15 >> 1) & 3)) * 8;
  const int abase = (wr * 128 + l15) * 32;   // + i*512
  const int bbase = (wcn * 64 + l15) * 32;   // + j*512

  f32x4 acc[8][4];
#pragma unroll
  for (int i = 0; i < 8; ++i)
#pragma unroll
    for (int j = 0; j < 4; ++j) acc[i][j] = (f32x4){0.f, 0.f, 0.f, 0.f};

#define STAGE(T, BUF)                                                        \
  {                                                                          \
    const long kb = (long)(T) * 32;                                          \
    unsigned short* Asb = LDSU + (BUF) * 8192;                               \
    unsigned short* Bsb = LDSU + 32768 + (BUF) * 8192;                       \
    gload16(Ab + kb + gOff,            &Asb[ldsb]);                          \
    gload16(Ab + kb + gOff + 128L * K, &Asb[4096 + ldsb]);                   \
    gload16(Bb + kb + gOff,            &Bsb[ldsb]);                          \
    gload16(Bb + kb + gOff + 128L * K, &Bsb[4096 + ldsb]);                   \
  }

  // prologue: stage tiles 0,1 into buffers 0,1
  STAGE(0, 0)
  STAGE(1, 1)

  const int NT = K >> 5;
  for (int t = 0; t < NT; ++t) {
    if (t < NT - 1) { asm volatile("s_waitcnt vmcnt(4)" ::: "memory"); }
    else            { asm volatile("s_waitcnt vmcnt(0)" ::: "memory"); }
    if ((t & 1) == 0) SBAR;          // barrier every 2nd tile only
    if (t + 2 < NT) STAGE(t + 2, (t + 2) & 3)

    const unsigned short* Asc = LDSU + (t & 3) * 8192;
    const unsigned short* Bsc = LDSU + 32768 + (t & 3) * 8192;
    short8v Bf[4], Af[8];
#pragma unroll
    for (int j = 0; j < 4; ++j)
      Bf[j] = *(const short8v*)&Bsc[bbase + j * 512 + rdsw];
#pragma unroll
    for (int i = 0; i < 8; ++i)
      Af[i] = *(const short8v*)&Asc[abase + i * 512 + rdsw];

    __builtin_amdgcn_s_setprio(1);
#pragma unroll
    for (int i = 0; i < 8; ++i)
#pragma unroll
      for (int j = 0; j < 4; ++j)
        acc[i][j] = MFMA_BF16(Af[i], Bf[j], acc[i][j], 0, 0, 0);
    __builtin_amdgcn_s_setprio(0);
  }
#undef STAGE
  SBAR;   // all waves done with K-loop LDS -> safe to reuse as epilogue scratch

  const int row0 = bm * 256 + wr * 128;
  const int col0 = bn * 256 + wcn * 64;
  unsigned short* sc = LDSU;       // [256 rows][256 cols] bf16, cell-swizzled
  float* scf = (float*)LDSU;       // [128 rows][256 cols] fp32, cell-swizzled

  if constexpr (EPI == 1) {
    float* Cb = (float*)O0 + (long)bz * sC;
    const float g = gptr[0];
#pragma unroll
    for (int h = 0; h < 2; ++h) {
      if (wr == h) {
#pragma unroll
        for (int i = 0; i < 8; ++i)
#pragma unroll
          for (int j = 0; j < 4; ++j) {
            const int col = wcn * 64 + j * 16 + l15;
            const int cc = col >> 2, c3 = col & 3;
#pragma unroll
            for (int r = 0; r < 4; ++r) {
              const int rl = i * 16 + lk * 4 + r;     // [0,128)
              scf[rl * 256 + ((cc ^ (rl & 15)) << 2) + c3] = acc[i][j][r];
            }
          }
      }
      SBAR;
#pragma unroll
      for (int it = 0; it < 16; ++it) {
        const int rl = it * 8 + wv;                    // [0,128)
        const int rg = bm * 256 + h * 128 + rl;        // [0,2048)
        const int c = lane;                            // f32 cell [0,64)
        fl4 a4 = *(const fl4*)&scf[rl * 256 + ((c ^ (rl & 15)) << 2)];
        const int cg = bn * 256 + c * 4;
        us4 xv = *(const us4*)&xh[((long)bz * 2048 + rg) * 1024 + cg];
        fl4 tl = *(const fl4*)&tailor[bz * 1024 + cg];
        const float vs = Vsum[bz * 2048 + rg];
        fl4 o;
#pragma unroll
        for (int q = 0; q < 4; ++q) o[q] = b2f(xv[q]) + g * ((vs + a4[q]) * tl[q]);
        *(fl4*)&Cb[(long)rg * 1024 + cg] = o;
      }
      if (h == 0) SBAR;
    }
  } else if constexpr (EPI == 4) {
    // S[p][l] = invq[p]*invk[l]*acc; Srow[p] += scaled row sum; roundtrip -> us8 stores
    unsigned short* Cb = (unsigned short*)O0 + (long)bz * sC;
    float ivk[4];
#pragma unroll
    for (int j = 0; j < 4; ++j) ivk[j] = r3[bz * 1024 + col0 + j * 16 + l15];
#pragma unroll
    for (int i = 0; i < 8; ++i) {
      float ivq[4];
#pragma unroll
      for (int r = 0; r < 4; ++r) ivq[r] = r2[bz * 1024 + row0 + i * 16 + lk * 4 + r];
#pragma unroll
      for (int r = 0; r < 4; ++r) {
        const int rl = wr * 128 + i * 16 + lk * 4 + r;   // [0,256)
        float sm = 0.f;
#pragma unroll
        for (int j = 0; j < 4; ++j) {
          const float v = acc[i][j][r] * ivq[r] * ivk[j];
          sm += v;
          const int col = wcn * 64 + j * 16 + l15;
          sc[rl * 256 + (((col >> 3) ^ (rl & 15)) << 3) + (col & 7)] = f2b(v);
        }
        sm = red16(sm);
        if (l15 == 0) atomicAdd(&r1[(long)bz * 1024 + row0 + i * 16 + lk * 4 + r], sm);
      }
    }
    SBAR;
#pragma unroll
    for (int it = 0; it < 16; ++it) {
      const int rl = it * 16 + wv * 2 + (lane >> 5);    // [0,256)
      const int c = lane & 31;
      us8 v = *(const us8*)&sc[rl * 256 + ((c ^ (rl & 15)) << 3)];
      *(us8*)&Cb[(long)(bm * 256 + rl) * 1024 + bn * 256 + c * 8] = v;
    }
  } else {  // EPI == 5: merged QKV
    const int seg = bn >> 2;             // 0=Q, 1=K, 2=V
    const int b = bm >> 3;               // batch
    float bvj[4];
#pragma unroll
    for (int j = 0; j < 4; ++j) bvj[j] = bias[col0 + j * 16 + l15];
    const int colL0 = col0 & 1023;
    if (seg < 2) {
      // stage transposed: p = local col [0,256), m = local row [0,256)
#pragma unroll
      for (int i = 0; i < 8; ++i)
#pragma unroll
        for (int j = 0; j < 4; ++j) {
          const int p = wcn * 64 + j * 16 + l15;
          const int m = wr * 128 + i * 16 + lk * 4;    // aligned 4
          us4 o;
#pragma unroll
          for (int r = 0; r < 4; ++r) o[r] = f2b(acc[i][j][r] + bvj[j]);
          *(us4*)&sc[p * 256 + (((m >> 3) ^ (p & 15)) << 3) + (m & 7)] = o;
        }
      // col reductions (pre-stage values, in-register)
#pragma unroll
      for (int j = 0; j < 4; ++j) {
        const int colL = colL0 + j * 16 + l15;
        float ss = 0.f, sm = 0.f;
#pragma unroll
        for (int i = 0; i < 8; ++i)
#pragma unroll
          for (int r = 0; r < 4; ++r) {
            const float v = acc[i][j][r] + bvj[j];
            ss += v * v; sm += v;
          }
        ss = red4lk(ss);
        if (seg == 0) sm = red4lk(sm);
        if (lk == 0) {
          atomicAdd(&(seg == 0 ? r1 : r3)[(long)b * 1024 + colL], ss);
          if (seg == 0) atomicAdd(&r2[(long)b * 1024 + colL], sm);
        }
      }
      SBAR;
      unsigned short* tp = (seg == 0 ? (unsigned short*)O0 : (unsigned short*)O1)
                           + (long)b * 2097152;        // 1024*2048 per batch
      const int P0 = (bn & 3) * 256;
      const int M0 = (bm & 7) * 256;
#pragma unroll
      for (int it = 0; it < 16; ++it) {
        const int p = it * 16 + wv * 2 + (lane >> 5);  // [0,256)
        const int c = lane & 31;
        us8 v = *(const us8*)&sc[p * 256 + ((c ^ (p & 15)) << 3)];
        *(us8*)&tp[(long)(P0 + p) * 2048 + M0 + c * 8] = v;
      }
    } else {
      // V: stage normal layout + row sums
#pragma unroll
      for (int i = 0; i < 8; ++i)
#pragma unroll
        for (int r = 0; r < 4; ++r) {
          const int rl = wr * 128 + i * 16 + lk * 4 + r;  // [0,256)
          float sm = 0.f;
#pragma unroll
          for (int j = 0; j < 4; ++j) {
            const float v = acc[i][j][r] + bvj[j];
            sm += v;
            const int col = wcn * 64 + j * 16 + l15;
            sc[rl * 256 + (((col >> 3) ^ (rl & 15)) << 3) + (col & 7)] = f2b(v);
          }
          sm = red16(sm);
          if (l15 == 0) atomicAdd(&r4[row0 + i * 16 + lk * 4 + r], sm);
        }
      SBAR;
      unsigned short* outp = (unsigned short*)O2;
      const int C0 = (bn & 3) * 256;
#pragma unroll
      for (int it = 0; it < 16; ++it) {
        const int rl = it * 16 + wv * 2 + (lane >> 5);
        const int c = lane & 31;
        us8 v = *(const us8*)&sc[rl * 256 + ((c ^ (rl & 15)) << 3)];
        *(us8*)&outp[(long)(bm * 256 + rl) * 1024 + C0 + c * 8] = v;
      }
    }
  }
}

extern "C" void kernel_launch(void* const* d_in, const int* in_sizes, int n_in,
                              void* d_out, int out_size, void* d_ws, size_t ws_size,
                              hipStream_t stream) {
  (void)in_sizes; (void)n_in; (void)out_size;
  const float* x     = (const float*)d_in[0];
  const float* Wq    = (const float*)d_in[1];
  const float* bq    = (const float*)d_in[2];
  const float* Wk    = (const float*)d_in[3];
  const float* bk    = (const float*)d_in[4];
  const float* Wv    = (const float*)d_in[5];
  const float* bv    = (const float*)d_in[6];
  const float* gamma = (const float*)d_in[7];

  // B=16, C=2048, L=D=1024
  const long NE = 16L * 2048 * 1024;
  const long BUF = NE * 2;                    // bytes per bf16 tensor

  char* w = (char*)d_ws;
  unsigned short* QT  = (unsigned short*)(w);            // [16][1024][2048] bf16
  unsigned short* KT  = (unsigned short*)(w + BUF);      // [16][1024][2048] bf16
  unsigned short* Vh  = (unsigned short*)(w + 2 * BUF);  // [32768][1024]
  unsigned short* xh  = (unsigned short*)(w + 3 * BUF);  // live to the end
  unsigned short* S   = (unsigned short*)(w + 4 * BUF);  // [16][1024][1024] (33.5 MB)
  size_t off = 4 * (size_t)BUF + (size_t)BUF / 2 + 4096;
  unsigned short* Wqkvh = (unsigned short*)(w + off); off += 3 * 2097152;  // Wq|Wk|Wv contiguous
  char* accbase = w + off;
  float* pq     = (float*)(w + off); off += 65536;       // col sumsq of Q  (16x1024)
  float* qsum   = (float*)(w + off); off += 65536;       // col sum of Q
  float* pk     = (float*)(w + off); off += 65536;       // col sumsq of K
  float* Vsum   = (float*)(w + off); off += 131072;      // row sum of V    (16x2048)
  float* Srow   = (float*)(w + off); off += 65536;       // row sum of scaled S (16x1024)
  const size_t accbytes = (size_t)(w + off - accbase);
  float* invq   = (float*)(w + off); off += 65536;
  float* invk   = (float*)(w + off); off += 65536;
  float* tailor = (float*)(w + off); off += 65536;
  float* bqkv   = (float*)(w + off); off += 12288;
  if (ws_size < off) return;

  // 0) zero atomic accumulators
  hipMemsetAsync(accbase, 0, accbytes, stream);

  // 1) casts + bias concat
  k_f32_to_bf16<<<dim3((unsigned)(NE / 1024)), 256, 0, stream>>>(x, xh, NE);
  k_f32_to_bf16<<<dim3(1024), 256, 0, stream>>>(Wq, Wqkvh, 1048576);
  k_f32_to_bf16<<<dim3(1024), 256, 0, stream>>>(Wk, Wqkvh + 1048576, 1048576);
  k_f32_to_bf16<<<dim3(1024), 256, 0, stream>>>(Wv, Wqkvh + 2097152, 1048576);
  k_bias_cat<<<dim3(12), 256, 0, stream>>>(bq, bk, bv, bqkv);

  // 2) merged QKV GEMM: M=32768, N=3072, K=1024; Q,K stored transposed + fused reductions
  k_g256<5><<<dim3(12, 128, 1), 512, 0, stream>>>(
      xh, Wqkvh, QT, KT, Vh, 1024, 0, 0, 0, bqkv,
      pq, qsum, pk, Vsum, nullptr, nullptr, nullptr, nullptr);

  // 3) inverse norms
  k_norms_fin<<<dim3(64), 256, 0, stream>>>(pq, pk, invq, invk);

  // 4) S = invq.(QT x KT^T).invk per batch (M=N=1024, K=2048) + scaled row sums
  k_g256<4><<<dim3(4, 4, 16), 512, 0, stream>>>(
      QT, KT, S, nullptr, nullptr, 2048, 1024L * 2048, 1024L * 2048, 1024L * 1024,
      nullptr, Srow, invq, invk, nullptr, nullptr, nullptr, nullptr, nullptr);

  // 5) tailor
  k_tailor_fin<<<dim3(64), 256, 0, stream>>>(Srow, invq, qsum, tailor);

  // 6) out = xh + gamma*(Vsum + V x S^T) * tailor   (M=2048/batch, N=1024, K=1024)
  k_g256<1><<<dim3(4, 8, 16), 512, 0, stream>>>(
      Vh, S, d_out, nullptr, nullptr, 1024, 2048L * 1024, 1024L * 1024, 2048L * 1024,
      nullptr, nullptr, nullptr, nullptr, nullptr, xh, Vsum, tailor, gamma);
}